// Round 9
// baseline (976.086 us; speedup 1.0000x reference)
//
#include <hip/hip_runtime.h>

#define N_NODES 100000
#define N_EDGES 1600000
#define FEAT 128
#define LAYERS 4
#define SCAN_BLK 256
#define N_SCAN_BLKS ((N_NODES + SCAN_BLK - 1) / SCAN_BLK)  // 391
#define NBKT ((N_NODES + 511) >> 9)                        // 196 buckets x 512 nodes
#define P1_CHUNK 4096
#define N_P1_BLKS ((N_EDGES + P1_CHUNK - 1) / P1_CHUNK)    // 391
#define GEMM_TILES ((N_NODES + 63) / 64)                   // 1563
#define GEMM_GRID ((GEMM_TILES + 1) / 2)                   // 782

typedef __attribute__((ext_vector_type(8))) short bf16x8;
typedef __attribute__((ext_vector_type(4))) float f32x4;

__device__ __forceinline__ unsigned short f2b(float f) {   // f32 -> bf16 RNE
    union { float f; unsigned int u; } v; v.f = f;
    unsigned int u = v.u;
    return (unsigned short)((u + 0x7fffu + ((u >> 16) & 1u)) >> 16);
}

// packed max of 2x bf16 (valid for non-negative bf16: bit pattern is monotone)
__device__ __forceinline__ unsigned int pkmax(unsigned int a, unsigned int b) {
    unsigned int r;
    asm("v_pk_max_u16 %0, %1, %2" : "=v"(r) : "v"(a), "v"(b));
    return r;
}

// ---------------- CSR build (bucketed) ----------------

__global__ __launch_bounds__(256) void count_deg_kernel(const int* __restrict__ dst,
                                                        int* __restrict__ deg,
                                                        int* __restrict__ bkt_cnt) {
    __shared__ int h[NBKT];
    for (int i = threadIdx.x; i < NBKT; i += 256) h[i] = 0;
    __syncthreads();
    const int base = blockIdx.x * P1_CHUNK;
    for (int i = threadIdx.x; i < P1_CHUNK; i += 256) {
        int e = base + i;
        if (e < N_EDGES) {
            int d = dst[e];
            atomicAdd(&deg[d], 1);
            atomicAdd(&h[d >> 9], 1);
        }
    }
    __syncthreads();
    for (int i = threadIdx.x; i < NBKT; i += 256)
        if (h[i]) atomicAdd(&bkt_cnt[i], h[i]);
}

__global__ __launch_bounds__(SCAN_BLK) void blk_sum_kernel(const int* __restrict__ deg,
                                                           int* __restrict__ blk_sums) {
    int i = blockIdx.x * SCAN_BLK + threadIdx.x;
    int v = (i < N_NODES) ? deg[i] : 0;
#pragma unroll
    for (int off = 32; off; off >>= 1) v += __shfl_down(v, off, 64);
    __shared__ int ws_[SCAN_BLK / 64];
    if ((threadIdx.x & 63) == 0) ws_[threadIdx.x >> 6] = v;
    __syncthreads();
    if (threadIdx.x == 0) {
        int s = 0;
#pragma unroll
        for (int w = 0; w < SCAN_BLK / 64; ++w) s += ws_[w];
        blk_sums[blockIdx.x] = s;
    }
}

__global__ __launch_bounds__(512) void scan_all_kernel(int* __restrict__ blk_sums,
                                                       const int* __restrict__ bkt_cnt,
                                                       int* __restrict__ bkt_start,
                                                       int* __restrict__ bkt_cursor) {
    __shared__ int s[512];
    __shared__ int b[256];
    const int t = threadIdx.x;
    s[t] = (t < N_SCAN_BLKS) ? blk_sums[t] : 0;
    if (t < 256) b[t] = (t < NBKT) ? bkt_cnt[t] : 0;
    __syncthreads();
    for (int off = 1; off < 512; off <<= 1) {
        int v = (t >= off) ? s[t - off] : 0;
        __syncthreads();
        s[t] += v;
        __syncthreads();
    }
    for (int off = 1; off < 256; off <<= 1) {
        int v = (t < 256 && t >= off) ? b[t - off] : 0;
        __syncthreads();
        if (t < 256) b[t] += v;
        __syncthreads();
    }
    if (t < N_SCAN_BLKS) blk_sums[t] = (t == 0) ? 0 : s[t - 1];
    if (t < NBKT) {
        int st = (t == 0) ? 0 : b[t - 1];
        bkt_start[t] = st;
        bkt_cursor[t] = st;
    }
    if (t == 0) bkt_start[NBKT] = N_EDGES;
}

__global__ __launch_bounds__(SCAN_BLK) void write_rowptr_kernel(
    const int* __restrict__ deg, const int* __restrict__ blk_off,
    int* __restrict__ row_ptr) {
    __shared__ int s[SCAN_BLK];
    const int t = threadIdx.x;
    const int i = blockIdx.x * SCAN_BLK + t;
    int v = (i < N_NODES) ? deg[i] : 0;
    s[t] = v;
    __syncthreads();
    for (int off = 1; off < SCAN_BLK; off <<= 1) {
        int u = (t >= off) ? s[t - off] : 0;
        __syncthreads();
        s[t] += u;
        __syncthreads();
    }
    int excl = s[t] - v + blk_off[blockIdx.x];
    if (i < N_NODES) row_ptr[i] = excl;
    if (i == 0) row_ptr[N_NODES] = N_EDGES;
}

__global__ __launch_bounds__(256) void bucket_scatter_kernel(
    const int* __restrict__ src, const int* __restrict__ dst,
    int* __restrict__ bkt_cursor, int2* __restrict__ ebuf) {
    __shared__ int h[NBKT], base[NBKT], cur[NBKT];
    for (int i = threadIdx.x; i < NBKT; i += 256) h[i] = 0;
    __syncthreads();
    const int b0 = blockIdx.x * P1_CHUNK;
    for (int i = threadIdx.x; i < P1_CHUNK; i += 256) {
        int e = b0 + i;
        if (e < N_EDGES) atomicAdd(&h[dst[e] >> 9], 1);
    }
    __syncthreads();
    for (int i = threadIdx.x; i < NBKT; i += 256) {
        cur[i] = 0;
        base[i] = h[i] ? atomicAdd(&bkt_cursor[i], h[i]) : 0;
    }
    __syncthreads();
    for (int i = threadIdx.x; i < P1_CHUNK; i += 256) {
        int e = b0 + i;
        if (e < N_EDGES) {
            int d = dst[e];
            int bk = d >> 9;
            int pos = base[bk] + atomicAdd(&cur[bk], 1);
            ebuf[pos] = make_int2(src[e], d);
        }
    }
}

__global__ __launch_bounds__(256) void csr_scatter_kernel(
    const int2* __restrict__ ebuf, const int* __restrict__ bkt_start,
    const int* __restrict__ row_ptr, int* __restrict__ edge_src) {
    __shared__ int cur[512];
    const int bk = blockIdx.x;
    const int n0 = bk << 9;
    for (int i = threadIdx.x; i < 512; i += 256) {
        int n = n0 + i;
        cur[i] = (n < N_NODES) ? row_ptr[n] : 0;
    }
    __syncthreads();
    const int s = bkt_start[bk], e = bkt_start[bk + 1];
    for (int i = s + threadIdx.x; i < e; i += 256) {
        int2 ed = ebuf[i];
        int pos = atomicAdd(&cur[ed.y - n0], 1);
        edge_src[pos] = ed.x;
    }
}

// ---------------- weight convert: Wt[m][n][k] = bf16(W[m][k][n]) ----------------
__global__ __launch_bounds__(256) void convert_wt_kernel(
    const float* __restrict__ Wp, const float* __restrict__ Ws,
    const float* __restrict__ Wn, unsigned short* __restrict__ wt) {
    __shared__ float tile[64][65];
    const int m = blockIdx.x >> 2;
    const int tij = blockIdx.x & 3;
    const int ti = tij >> 1, tj = tij & 1;
    const float* W = (m < 4) ? Wp + (size_t)m * 16384
                   : (m < 8) ? Ws + (size_t)(m - 4) * 16384
                             : Wn + (size_t)(m - 8) * 16384;
#pragma unroll
    for (int i = 0; i < 16; ++i) {
        int e = i * 256 + threadIdx.x;
        int r = e >> 6, c = e & 63;
        tile[r][c] = W[(size_t)(ti * 64 + r) * 128 + tj * 64 + c];
    }
    __syncthreads();
#pragma unroll
    for (int i = 0; i < 16; ++i) {
        int e = i * 256 + threadIdx.x;
        int r = e >> 6, c = e & 63;
        wt[(size_t)m * 16384 + (size_t)(tj * 64 + r) * 128 + ti * 64 + c] = f2b(tile[c][r]);
    }
}

// ---------------- MFMA GEMM, swapped operands, 2-tile pipelined ----------------
// D col = lane&15 -> NODE; D row = 4*(lane>>4)+reg -> 4 consecutive features.
// MODE 0: h  = bf16(relu(x@W1+bias))           -> yh SLICE-MAJOR [ft][n][16]
// MODE 1: x' = relu(x@W1 + p@W2 + bias)        -> yx bf16 row-major
//         h' = bf16(relu(x'@Wnt + bias_n))     -> yh SLICE-MAJOR
// MODE 2: x' -> yf f32 row-major (final out)
// p input is SLICE-MAJOR [s][n][16].
// Pipeline: prefetch regs for tile0 (x then p), stage-from-regs; while MFMA of
// tile0 runs, issue tile1's loads. Per-register vmcnt tracking (compiler) means
// pass-0 MFMA overlaps the in-flight p loads and tile1 loads.
template <int MODE, bool AF32>
__global__ __launch_bounds__(256, 3) void gemm_kernel(
    const void* __restrict__ xv, const unsigned short* __restrict__ p,
    const unsigned short* __restrict__ W1t, const unsigned short* __restrict__ W2t,
    const float* __restrict__ bias,
    const unsigned short* __restrict__ Wnt, const float* __restrict__ bias_n,
    float* __restrict__ yf, unsigned short* __restrict__ yx,
    unsigned short* __restrict__ yh) {
    __shared__ unsigned short xs[64 * FEAT];  // 16 KB, XOR-swizzled
    const int tid = threadIdx.x;
    const int wv = tid >> 6;
    const int lane = tid & 63;
    const int l15 = lane & 15;
    const int lhi = lane >> 4;
    const int nrow = 16 * wv + l15;     // node-in-tile this lane owns
    const int fsub = 4 * lhi;
    const int tile0 = blockIdx.x * 2;

    float4 rxf[8];   // AF32 x prefetch
    uint4 rxb[4];    // bf16 x prefetch
    uint4 rp[4];     // p prefetch
    f32x4 acc[8];

    auto issue_x = [&](int tile) {
        if (AF32) {
            const float* x = (const float*)xv;
#pragma unroll
            for (int i = 0; i < 4; ++i) {
                int chunk = i * 256 + tid;
                int row = chunk >> 4, c8 = chunk & 15;
                int n = tile * 64 + row;
                rxf[2 * i] = make_float4(0.f, 0.f, 0.f, 0.f);
                rxf[2 * i + 1] = rxf[2 * i];
                if (n < N_NODES) {
                    const float4* g = (const float4*)(x + (size_t)n * FEAT + c8 * 8);
                    rxf[2 * i] = g[0];
                    rxf[2 * i + 1] = g[1];
                }
            }
        } else {
            const unsigned short* xb = (const unsigned short*)xv;
#pragma unroll
            for (int i = 0; i < 4; ++i) {
                int chunk = i * 256 + tid;
                int row = chunk >> 4, c8 = chunk & 15;
                int n = tile * 64 + row;
                rxb[i] = make_uint4(0u, 0u, 0u, 0u);
                if (n < N_NODES) rxb[i] = *(const uint4*)(xb + (size_t)n * FEAT + c8 * 8);
            }
        }
    };
    auto stage_x = [&]() {
#pragma unroll
        for (int i = 0; i < 4; ++i) {
            int chunk = i * 256 + tid;
            int row = chunk >> 4, c8 = chunk & 15;
            int byte = (row * 256 + c8 * 16) ^ ((row & 7) << 4);
            if (AF32) {
                float4 v0 = rxf[2 * i], v1 = rxf[2 * i + 1];
                unsigned short hh[8];
                hh[0] = f2b(v0.x); hh[1] = f2b(v0.y); hh[2] = f2b(v0.z); hh[3] = f2b(v0.w);
                hh[4] = f2b(v1.x); hh[5] = f2b(v1.y); hh[6] = f2b(v1.z); hh[7] = f2b(v1.w);
                *(bf16x8*)((char*)xs + byte) = *(bf16x8*)hh;
            } else {
                *(uint4*)((char*)xs + byte) = rxb[i];
            }
        }
    };
    auto issue_p = [&](int tile) {
#pragma unroll
        for (int i = 0; i < 4; ++i) {
            int chunk = i * 256 + tid;
            int row = chunk & 63, c8 = chunk >> 6;
            int n = tile * 64 + row;
            rp[i] = make_uint4(0u, 0u, 0u, 0u);
            if (n < N_NODES)
                rp[i] = *(const uint4*)(p + ((size_t)(c8 >> 1) * N_NODES + n) * 16 + (c8 & 1) * 8);
        }
    };
    auto stage_p = [&]() {
#pragma unroll
        for (int i = 0; i < 4; ++i) {
            int chunk = i * 256 + tid;
            int row = chunk & 63, c8 = chunk >> 6;
            int byte = (row * 256 + c8 * 16) ^ ((row & 7) << 4);
            *(uint4*)((char*)xs + byte) = rp[i];
        }
    };
    auto mfma_pass = [&](const unsigned short* Wt) {
        bf16x8 xfrag[4];
#pragma unroll
        for (int kk = 0; kk < 4; ++kk) {
            int byte = (nrow * 256 + (kk * 32 + lhi * 8) * 2) ^ ((nrow & 7) << 4);
            xfrag[kk] = *(const bf16x8*)((const char*)xs + byte);
        }
#pragma unroll
        for (int ft = 0; ft < 8; ++ft) {
            const unsigned short* wrow = Wt + (size_t)(ft * 16 + l15) * FEAT;
#pragma unroll
            for (int kk = 0; kk < 4; ++kk) {
                bf16x8 wfrag = *(const bf16x8*)(wrow + kk * 32 + lhi * 8);
                acc[ft] = __builtin_amdgcn_mfma_f32_16x16x32_bf16(wfrag, xfrag[kk], acc[ft], 0, 0, 0);
            }
        }
    };

    issue_x(tile0);
    if (MODE >= 1) issue_p(tile0);

#pragma unroll
    for (int t = 0; t < 2; ++t) {
        const int tile = tile0 + t;
        const int nglob = tile * 64 + nrow;
#pragma unroll
        for (int q = 0; q < 8; ++q) acc[q] = (f32x4)(0.f);

        __syncthreads();             // xs free from previous tile's readers
        stage_x();                   // waits only on x loads
        __syncthreads();
        if (t == 0) issue_x(tile0 + 1);    // overlap with W1 MFMA
        mfma_pass(W1t);

        if (MODE >= 1) {
            __syncthreads();
            stage_p();               // waits only on p loads
            __syncthreads();
            if (t == 0) issue_p(tile0 + 1);  // overlap with W2 MFMA
            mfma_pass(W2t);
        }

        // epilogue 1: bias + relu; wide stores
        if (MODE == 1) __syncthreads();  // all xs reads done before x' overwrite
#pragma unroll
        for (int ft = 0; ft < 8; ++ft) {
            float4 bv = ((const float4*)bias)[ft * 4 + lhi];
            float v0 = fmaxf(acc[ft][0] + bv.x, 0.f);
            float v1 = fmaxf(acc[ft][1] + bv.y, 0.f);
            float v2 = fmaxf(acc[ft][2] + bv.z, 0.f);
            float v3 = fmaxf(acc[ft][3] + bv.w, 0.f);
            uint2 pk = make_uint2((unsigned)f2b(v0) | ((unsigned)f2b(v1) << 16),
                                  (unsigned)f2b(v2) | ((unsigned)f2b(v3) << 16));
            if (MODE == 0) {
                if (nglob < N_NODES)
                    *(uint2*)(yh + ((size_t)ft * N_NODES + nglob) * 16 + fsub) = pk;
            } else if (MODE == 2) {
                if (nglob < N_NODES)
                    *(float4*)(yf + (size_t)nglob * FEAT + ft * 16 + fsub) =
                        make_float4(v0, v1, v2, v3);
            } else {
                if (nglob < N_NODES)
                    *(uint2*)(yx + (size_t)nglob * FEAT + ft * 16 + fsub) = pk;
                int byte = (nrow * 256 + (ft * 16 + fsub) * 2) ^ ((nrow & 7) << 4);
                *(uint2*)((char*)xs + byte) = pk;
            }
        }

        // pass 3 (MODE 1): h' = relu(x' @ Wnt + bias_n) -> slice-major
        if (MODE == 1) {
            __syncthreads();
#pragma unroll
            for (int q = 0; q < 8; ++q) acc[q] = (f32x4)(0.f);
            mfma_pass(Wnt);
#pragma unroll
            for (int ft = 0; ft < 8; ++ft) {
                float4 bv = ((const float4*)bias_n)[ft * 4 + lhi];
                float v0 = fmaxf(acc[ft][0] + bv.x, 0.f);
                float v1 = fmaxf(acc[ft][1] + bv.y, 0.f);
                float v2 = fmaxf(acc[ft][2] + bv.z, 0.f);
                float v3 = fmaxf(acc[ft][3] + bv.w, 0.f);
                uint2 pk = make_uint2((unsigned)f2b(v0) | ((unsigned)f2b(v1) << 16),
                                      (unsigned)f2b(v2) | ((unsigned)f2b(v3) << 16));
                if (nglob < N_NODES)
                    *(uint2*)(yh + ((size_t)ft * N_NODES + nglob) * 16 + fsub) = pk;
            }
        }
    }
}

// ---------------- segment max, XCD-pinned slices, 4-node ILP ----------------
__global__ __launch_bounds__(256) void seg_max_kernel(
    const unsigned short* __restrict__ hs, const int* __restrict__ row_ptr,
    const int* __restrict__ edge_src, unsigned short* __restrict__ pooled) {
    const int s = blockIdx.x & 7;
    const int g = blockIdx.x >> 3;            // node group of 16
    const int wv = threadIdx.x >> 6;
    const int lane = threadIdx.x & 63;
    const int qn = lane >> 4;                 // node-in-wave 0..3
    const int slot = (lane >> 2) & 3;         // edge slot 0..3
    const int f = lane & 3;                   // feat quad 0..3
    int node = g * 16 + wv * 4 + qn;
    const bool valid = node < N_NODES;
    node = valid ? node : N_NODES - 1;
    const unsigned short* hbase = hs + (size_t)s * N_NODES * 16;

    const int start = row_ptr[node];
    const int end = row_ptr[node + 1];
    unsigned int a0 = 0u, a1 = 0u;            // packed 4x bf16 (>=0)
    int i = start + slot;
    for (; i + 4 < end; i += 8) {
        const uint2 v0 = *(const uint2*)(hbase + (size_t)edge_src[i] * 16 + f * 4);
        const uint2 v1 = *(const uint2*)(hbase + (size_t)edge_src[i + 4] * 16 + f * 4);
        a0 = pkmax(a0, v0.x); a1 = pkmax(a1, v0.y);
        a0 = pkmax(a0, v1.x); a1 = pkmax(a1, v1.y);
    }
    if (i < end) {
        const uint2 v0 = *(const uint2*)(hbase + (size_t)edge_src[i] * 16 + f * 4);
        a0 = pkmax(a0, v0.x); a1 = pkmax(a1, v0.y);
    }
    a0 = pkmax(a0, __shfl_xor(a0, 4, 64));
    a1 = pkmax(a1, __shfl_xor(a1, 4, 64));
    a0 = pkmax(a0, __shfl_xor(a0, 8, 64));
    a1 = pkmax(a1, __shfl_xor(a1, 8, 64));
    if (slot == 0 && valid) {
        *(uint2*)(pooled + ((size_t)s * N_NODES + node) * 16 + f * 4) = make_uint2(a0, a1);
    }
}

// ---------------- launch ----------------
// ws (~148 MB < proven 161): edge_src 6.4 | ebuf 12.8 | deg 0.4 | bkt_cnt 1K |
// row_ptr 0.4 | blk_sums 2K | bkt_start 1K | bkt_cursor 1K | wt 0.39 |
// bufH 25.6 (slice-major) | bufP 25.6 (slice-major) | bufX0 25.6 | bufX1 25.6
// x chain: feats(f32) -> X0 -> X1 -> X0 -> d_out(f32)

extern "C" void kernel_launch(void* const* d_in, const int* in_sizes, int n_in,
                              void* d_out, int out_size, void* d_ws, size_t ws_size,
                              hipStream_t stream) {
    const float* feats = (const float*)d_in[0];
    const float* Wp = (const float*)d_in[1];
    const float* bp = (const float*)d_in[2];
    const float* Ws = (const float*)d_in[3];
    const float* Wn = (const float*)d_in[4];
    const float* bb = (const float*)d_in[5];
    const int* src = (const int*)d_in[6];
    const int* dst = (const int*)d_in[7];
    float* out = (float*)d_out;

    const size_t NF = (size_t)N_NODES * FEAT;
    char* ws = (char*)d_ws;
    int* edge_src = (int*)ws;    ws += (size_t)N_EDGES * sizeof(int);
    int2* ebuf = (int2*)ws;      ws += (size_t)N_EDGES * sizeof(int2);
    int* deg = (int*)ws;         ws += (size_t)N_NODES * sizeof(int);
    int* bkt_cnt = (int*)ws;     ws += 256 * sizeof(int);
    int* row_ptr = (int*)ws;     ws += (size_t)(N_NODES + 4) * sizeof(int);
    int* blk_sums = (int*)ws;    ws += 512 * sizeof(int);
    int* bkt_start = (int*)ws;   ws += 256 * sizeof(int);
    int* bkt_cursor = (int*)ws;  ws += 256 * sizeof(int);
    unsigned short* wt = (unsigned short*)ws;    ws += (size_t)12 * 16384 * sizeof(unsigned short);
    unsigned short* bufH = (unsigned short*)ws;  ws += NF * sizeof(unsigned short);
    unsigned short* bufP = (unsigned short*)ws;  ws += NF * sizeof(unsigned short);
    unsigned short* bufX0 = (unsigned short*)ws; ws += NF * sizeof(unsigned short);
    unsigned short* bufX1 = (unsigned short*)ws;

    // CSR build (deg & bkt_cnt adjacent -> single memset)
    hipMemsetAsync(deg, 0, ((size_t)N_NODES + 256) * sizeof(int), stream);
    count_deg_kernel<<<N_P1_BLKS, 256, 0, stream>>>(dst, deg, bkt_cnt);
    blk_sum_kernel<<<N_SCAN_BLKS, SCAN_BLK, 0, stream>>>(deg, blk_sums);
    scan_all_kernel<<<1, 512, 0, stream>>>(blk_sums, bkt_cnt, bkt_start, bkt_cursor);
    write_rowptr_kernel<<<N_SCAN_BLKS, SCAN_BLK, 0, stream>>>(deg, blk_sums, row_ptr);
    bucket_scatter_kernel<<<N_P1_BLKS, 256, 0, stream>>>(src, dst, bkt_cursor, ebuf);
    csr_scatter_kernel<<<NBKT, 256, 0, stream>>>(ebuf, bkt_start, row_ptr, edge_src);
    convert_wt_kernel<<<48, 256, 0, stream>>>(Wp, Ws, Wn, wt);

    const int seg_grid = ((N_NODES + 15) / 16) * 8;   // 6250 groups x 8 slices

    const unsigned short* xb[LAYERS] = {nullptr, bufX0, bufX1, bufX0};
    unsigned short* xo[LAYERS] = {bufX0, bufX1, bufX0, nullptr};

    // layer 0 h_pool
    gemm_kernel<0, true><<<GEMM_GRID, 256, 0, stream>>>(
        feats, nullptr, wt, nullptr, bp, nullptr, nullptr, nullptr, nullptr, bufH);

    for (int l = 0; l < LAYERS; ++l) {
        const unsigned short* WsT = wt + (size_t)(4 + l) * 16384;
        const unsigned short* WnT = wt + (size_t)(8 + l) * 16384;
        const float* bl = bb + (size_t)l * FEAT;

        seg_max_kernel<<<seg_grid, 256, 0, stream>>>(bufH, row_ptr, edge_src, bufP);

        if (l == 0) {
            gemm_kernel<1, true><<<GEMM_GRID, 256, 0, stream>>>(
                feats, bufP, WsT, WnT, bl, wt + (size_t)(l + 1) * 16384,
                bp + (size_t)(l + 1) * FEAT, nullptr, xo[l], bufH);
        } else if (l < LAYERS - 1) {
            gemm_kernel<1, false><<<GEMM_GRID, 256, 0, stream>>>(
                xb[l], bufP, WsT, WnT, bl, wt + (size_t)(l + 1) * 16384,
                bp + (size_t)(l + 1) * FEAT, nullptr, xo[l], bufH);
        } else {
            gemm_kernel<2, false><<<GEMM_GRID, 256, 0, stream>>>(
                xb[l], bufP, WsT, WnT, bl, nullptr, nullptr, out, nullptr, nullptr);
        }
    }
}

// Round 10
// 859.148 us; speedup vs baseline: 1.1361x; 1.1361x over previous
//
#include <hip/hip_runtime.h>

#define N_NODES 100000
#define N_EDGES 1600000
#define FEAT 128
#define LAYERS 4
#define SCAN_BLK 256
#define N_SCAN_BLKS ((N_NODES + SCAN_BLK - 1) / SCAN_BLK)  // 391
#define NBKT ((N_NODES + 511) >> 9)                        // 196 buckets x 512 nodes
#define P1_CHUNK 4096
#define N_P1_BLKS ((N_EDGES + P1_CHUNK - 1) / P1_CHUNK)    // 391
#define GEMM_GRID ((N_NODES + 63) / 64)                    // 1563

typedef __attribute__((ext_vector_type(8))) short bf16x8;
typedef __attribute__((ext_vector_type(4))) float f32x4;

__device__ __forceinline__ unsigned short f2b(float f) {   // f32 -> bf16 RNE
    union { float f; unsigned int u; } v; v.f = f;
    unsigned int u = v.u;
    return (unsigned short)((u + 0x7fffu + ((u >> 16) & 1u)) >> 16);
}

// packed max of 2x bf16 (valid for non-negative bf16: bit pattern is monotone)
__device__ __forceinline__ unsigned int pkmax(unsigned int a, unsigned int b) {
    unsigned int r;
    asm("v_pk_max_u16 %0, %1, %2" : "=v"(r) : "v"(a), "v"(b));
    return r;
}

// ---------------- CSR build (bucketed) ----------------

__global__ __launch_bounds__(256) void count_deg_kernel(const int* __restrict__ dst,
                                                        int* __restrict__ deg,
                                                        int* __restrict__ bkt_cnt) {
    __shared__ int h[NBKT];
    for (int i = threadIdx.x; i < NBKT; i += 256) h[i] = 0;
    __syncthreads();
    const int base = blockIdx.x * P1_CHUNK;
    for (int i = threadIdx.x; i < P1_CHUNK; i += 256) {
        int e = base + i;
        if (e < N_EDGES) {
            int d = dst[e];
            atomicAdd(&deg[d], 1);
            atomicAdd(&h[d >> 9], 1);
        }
    }
    __syncthreads();
    for (int i = threadIdx.x; i < NBKT; i += 256)
        if (h[i]) atomicAdd(&bkt_cnt[i], h[i]);
}

__global__ __launch_bounds__(SCAN_BLK) void blk_sum_kernel(const int* __restrict__ deg,
                                                           int* __restrict__ blk_sums) {
    int i = blockIdx.x * SCAN_BLK + threadIdx.x;
    int v = (i < N_NODES) ? deg[i] : 0;
#pragma unroll
    for (int off = 32; off; off >>= 1) v += __shfl_down(v, off, 64);
    __shared__ int ws_[SCAN_BLK / 64];
    if ((threadIdx.x & 63) == 0) ws_[threadIdx.x >> 6] = v;
    __syncthreads();
    if (threadIdx.x == 0) {
        int s = 0;
#pragma unroll
        for (int w = 0; w < SCAN_BLK / 64; ++w) s += ws_[w];
        blk_sums[blockIdx.x] = s;
    }
}

__global__ __launch_bounds__(512) void scan_all_kernel(int* __restrict__ blk_sums,
                                                       const int* __restrict__ bkt_cnt,
                                                       int* __restrict__ bkt_start,
                                                       int* __restrict__ bkt_cursor) {
    __shared__ int s[512];
    __shared__ int b[256];
    const int t = threadIdx.x;
    s[t] = (t < N_SCAN_BLKS) ? blk_sums[t] : 0;
    if (t < 256) b[t] = (t < NBKT) ? bkt_cnt[t] : 0;
    __syncthreads();
    for (int off = 1; off < 512; off <<= 1) {
        int v = (t >= off) ? s[t - off] : 0;
        __syncthreads();
        s[t] += v;
        __syncthreads();
    }
    for (int off = 1; off < 256; off <<= 1) {
        int v = (t < 256 && t >= off) ? b[t - off] : 0;
        __syncthreads();
        if (t < 256) b[t] += v;
        __syncthreads();
    }
    if (t < N_SCAN_BLKS) blk_sums[t] = (t == 0) ? 0 : s[t - 1];
    if (t < NBKT) {
        int st = (t == 0) ? 0 : b[t - 1];
        bkt_start[t] = st;
        bkt_cursor[t] = st;
    }
    if (t == 0) bkt_start[NBKT] = N_EDGES;
}

__global__ __launch_bounds__(SCAN_BLK) void write_rowptr_kernel(
    const int* __restrict__ deg, const int* __restrict__ blk_off,
    int* __restrict__ row_ptr) {
    __shared__ int s[SCAN_BLK];
    const int t = threadIdx.x;
    const int i = blockIdx.x * SCAN_BLK + t;
    int v = (i < N_NODES) ? deg[i] : 0;
    s[t] = v;
    __syncthreads();
    for (int off = 1; off < SCAN_BLK; off <<= 1) {
        int u = (t >= off) ? s[t - off] : 0;
        __syncthreads();
        s[t] += u;
        __syncthreads();
    }
    int excl = s[t] - v + blk_off[blockIdx.x];
    if (i < N_NODES) row_ptr[i] = excl;
    if (i == 0) row_ptr[N_NODES] = N_EDGES;
}

__global__ __launch_bounds__(256) void bucket_scatter_kernel(
    const int* __restrict__ src, const int* __restrict__ dst,
    int* __restrict__ bkt_cursor, int2* __restrict__ ebuf) {
    __shared__ int h[NBKT], base[NBKT], cur[NBKT];
    for (int i = threadIdx.x; i < NBKT; i += 256) h[i] = 0;
    __syncthreads();
    const int b0 = blockIdx.x * P1_CHUNK;
    for (int i = threadIdx.x; i < P1_CHUNK; i += 256) {
        int e = b0 + i;
        if (e < N_EDGES) atomicAdd(&h[dst[e] >> 9], 1);
    }
    __syncthreads();
    for (int i = threadIdx.x; i < NBKT; i += 256) {
        cur[i] = 0;
        base[i] = h[i] ? atomicAdd(&bkt_cursor[i], h[i]) : 0;
    }
    __syncthreads();
    for (int i = threadIdx.x; i < P1_CHUNK; i += 256) {
        int e = b0 + i;
        if (e < N_EDGES) {
            int d = dst[e];
            int bk = d >> 9;
            int pos = base[bk] + atomicAdd(&cur[bk], 1);
            ebuf[pos] = make_int2(src[e], d);
        }
    }
}

__global__ __launch_bounds__(256) void csr_scatter_kernel(
    const int2* __restrict__ ebuf, const int* __restrict__ bkt_start,
    const int* __restrict__ row_ptr, int* __restrict__ edge_src) {
    __shared__ int cur[512];
    const int bk = blockIdx.x;
    const int n0 = bk << 9;
    for (int i = threadIdx.x; i < 512; i += 256) {
        int n = n0 + i;
        cur[i] = (n < N_NODES) ? row_ptr[n] : 0;
    }
    __syncthreads();
    const int s = bkt_start[bk], e = bkt_start[bk + 1];
    for (int i = s + threadIdx.x; i < e; i += 256) {
        int2 ed = ebuf[i];
        int pos = atomicAdd(&cur[ed.y - n0], 1);
        edge_src[pos] = ed.x;
    }
}

// ---------------- weight convert: Wt[m][n][k] = bf16(W[m][k][n]) ----------------
__global__ __launch_bounds__(256) void convert_wt_kernel(
    const float* __restrict__ Wp, const float* __restrict__ Ws,
    const float* __restrict__ Wn, unsigned short* __restrict__ wt) {
    __shared__ float tile[64][65];
    const int m = blockIdx.x >> 2;
    const int tij = blockIdx.x & 3;
    const int ti = tij >> 1, tj = tij & 1;
    const float* W = (m < 4) ? Wp + (size_t)m * 16384
                   : (m < 8) ? Ws + (size_t)(m - 4) * 16384
                             : Wn + (size_t)(m - 8) * 16384;
#pragma unroll
    for (int i = 0; i < 16; ++i) {
        int e = i * 256 + threadIdx.x;
        int r = e >> 6, c = e & 63;
        tile[r][c] = W[(size_t)(ti * 64 + r) * 128 + tj * 64 + c];
    }
    __syncthreads();
#pragma unroll
    for (int i = 0; i < 16; ++i) {
        int e = i * 256 + threadIdx.x;
        int r = e >> 6, c = e & 63;
        wt[(size_t)m * 16384 + (size_t)(tj * 64 + r) * 128 + ti * 64 + c] = f2b(tile[c][r]);
    }
}

// ---------------- MFMA GEMM: single barrier, dual LDS halves ----------------
// Swapped operands: D col=lane&15 -> NODE, D row=4*(lane>>4)+reg -> 4 feats.
// Wave w's x-fragment reads touch ONLY rows [16w,16w+16) -> the only cross-wave
// dependency is the initial staging. So: issue x AND p loads up front (both in
// flight), stage into separate halves, ONE barrier, then W1/W2/epilogue/W3 with
// no further syncs (x' re-stage is wave-private rows).
// MODE 0: h  = bf16(relu(x@W1+bias))           -> yh SLICE-MAJOR [ft][n][16]
// MODE 1: x' = relu(x@W1 + p@W2 + bias)        -> yx bf16 row-major
//         h' = bf16(relu(x'@Wnt + bias_n))     -> yh SLICE-MAJOR
// MODE 2: x' -> yf f32 row-major (final out)
// p input is SLICE-MAJOR [s][n][16].
template <int MODE, bool AF32>
__global__ __launch_bounds__(256, 3) void gemm_kernel(
    const void* __restrict__ xv, const unsigned short* __restrict__ p,
    const unsigned short* __restrict__ W1t, const unsigned short* __restrict__ W2t,
    const float* __restrict__ bias,
    const unsigned short* __restrict__ Wnt, const float* __restrict__ bias_n,
    float* __restrict__ yf, unsigned short* __restrict__ yx,
    unsigned short* __restrict__ yh) {
    __shared__ unsigned short xs[2][64 * FEAT];  // 32 KB, XOR-swizzled halves
    const int tid = threadIdx.x;
    const int wv = tid >> 6;
    const int lane = tid & 63;
    const int l15 = lane & 15;
    const int lhi = lane >> 4;
    const int n0 = blockIdx.x * 64;
    const int nrow = 16 * wv + l15;     // node-in-tile this lane owns
    const int nglob = n0 + nrow;
    const int fsub = 4 * lhi;

    float4 rxf[8];   // AF32 x prefetch
    uint4 rxb[4];    // bf16 x prefetch
    uint4 rp[4];     // p prefetch
    f32x4 acc[8];

    // ---- issue ALL global loads up front (x and p both in flight) ----
    if (AF32) {
        const float* x = (const float*)xv;
#pragma unroll
        for (int i = 0; i < 4; ++i) {
            int chunk = i * 256 + tid;
            int row = chunk >> 4, c8 = chunk & 15;
            int n = n0 + row;
            rxf[2 * i] = make_float4(0.f, 0.f, 0.f, 0.f);
            rxf[2 * i + 1] = rxf[2 * i];
            if (n < N_NODES) {
                const float4* g = (const float4*)(x + (size_t)n * FEAT + c8 * 8);
                rxf[2 * i] = g[0];
                rxf[2 * i + 1] = g[1];
            }
        }
    } else {
        const unsigned short* xb = (const unsigned short*)xv;
#pragma unroll
        for (int i = 0; i < 4; ++i) {
            int chunk = i * 256 + tid;
            int row = chunk >> 4, c8 = chunk & 15;
            int n = n0 + row;
            rxb[i] = make_uint4(0u, 0u, 0u, 0u);
            if (n < N_NODES) rxb[i] = *(const uint4*)(xb + (size_t)n * FEAT + c8 * 8);
        }
    }
    if (MODE >= 1) {
#pragma unroll
        for (int i = 0; i < 4; ++i) {
            int chunk = i * 256 + tid;
            int row = chunk & 63, c8 = chunk >> 6;
            int n = n0 + row;
            rp[i] = make_uint4(0u, 0u, 0u, 0u);
            if (n < N_NODES)
                rp[i] = *(const uint4*)(p + ((size_t)(c8 >> 1) * N_NODES + n) * 16 + (c8 & 1) * 8);
        }
    }

    // ---- stage both halves, one barrier ----
#pragma unroll
    for (int i = 0; i < 4; ++i) {
        int chunk = i * 256 + tid;
        int row = chunk >> 4, c8 = chunk & 15;
        int byte = (row * 256 + c8 * 16) ^ ((row & 7) << 4);
        if (AF32) {
            float4 v0 = rxf[2 * i], v1 = rxf[2 * i + 1];
            unsigned short hh[8];
            hh[0] = f2b(v0.x); hh[1] = f2b(v0.y); hh[2] = f2b(v0.z); hh[3] = f2b(v0.w);
            hh[4] = f2b(v1.x); hh[5] = f2b(v1.y); hh[6] = f2b(v1.z); hh[7] = f2b(v1.w);
            *(bf16x8*)((char*)xs[0] + byte) = *(bf16x8*)hh;
        } else {
            *(uint4*)((char*)xs[0] + byte) = rxb[i];
        }
    }
    if (MODE >= 1) {
#pragma unroll
        for (int i = 0; i < 4; ++i) {
            int chunk = i * 256 + tid;
            int row = chunk & 63, c8 = chunk >> 6;
            int byte = (row * 256 + c8 * 16) ^ ((row & 7) << 4);
            *(uint4*)((char*)xs[1] + byte) = rp[i];
        }
    }
    __syncthreads();   // the ONLY barrier

    auto mfma_pass = [&](const unsigned short* Wt, const unsigned short* buf) {
        bf16x8 xfrag[4];
#pragma unroll
        for (int kk = 0; kk < 4; ++kk) {
            int byte = (nrow * 256 + (kk * 32 + lhi * 8) * 2) ^ ((nrow & 7) << 4);
            xfrag[kk] = *(const bf16x8*)((const char*)buf + byte);
        }
#pragma unroll
        for (int ft = 0; ft < 8; ++ft) {
            const unsigned short* wrow = Wt + (size_t)(ft * 16 + l15) * FEAT;
#pragma unroll
            for (int kk = 0; kk < 4; ++kk) {
                bf16x8 wfrag = *(const bf16x8*)(wrow + kk * 32 + lhi * 8);
                acc[ft] = __builtin_amdgcn_mfma_f32_16x16x32_bf16(wfrag, xfrag[kk], acc[ft], 0, 0, 0);
            }
        }
    };

#pragma unroll
    for (int q = 0; q < 8; ++q) acc[q] = (f32x4)(0.f);
    mfma_pass(W1t, xs[0]);
    if (MODE >= 1) mfma_pass(W2t, xs[1]);

    // ---- epilogue 1: bias + relu; wide stores; x' re-stage (wave-private rows,
    //      no barrier needed) ----
#pragma unroll
    for (int ft = 0; ft < 8; ++ft) {
        float4 bv = ((const float4*)bias)[ft * 4 + lhi];
        float v0 = fmaxf(acc[ft][0] + bv.x, 0.f);
        float v1 = fmaxf(acc[ft][1] + bv.y, 0.f);
        float v2 = fmaxf(acc[ft][2] + bv.z, 0.f);
        float v3 = fmaxf(acc[ft][3] + bv.w, 0.f);
        uint2 pk = make_uint2((unsigned)f2b(v0) | ((unsigned)f2b(v1) << 16),
                              (unsigned)f2b(v2) | ((unsigned)f2b(v3) << 16));
        if (MODE == 0) {
            if (nglob < N_NODES)
                *(uint2*)(yh + ((size_t)ft * N_NODES + nglob) * 16 + fsub) = pk;
        } else if (MODE == 2) {
            if (nglob < N_NODES)
                *(float4*)(yf + (size_t)nglob * FEAT + ft * 16 + fsub) =
                    make_float4(v0, v1, v2, v3);
        } else {
            if (nglob < N_NODES)
                *(uint2*)(yx + (size_t)nglob * FEAT + ft * 16 + fsub) = pk;
            int byte = (nrow * 256 + (ft * 16 + fsub) * 2) ^ ((nrow & 7) << 4);
            *(uint2*)((char*)xs[0] + byte) = pk;   // own rows only
        }
    }

    // ---- pass 3 (MODE 1): h' = relu(x' @ Wnt + bias_n) -> slice-major ----
    if (MODE == 1) {
#pragma unroll
        for (int q = 0; q < 8; ++q) acc[q] = (f32x4)(0.f);
        mfma_pass(Wnt, xs[0]);   // reads own rows, just written by this wave
#pragma unroll
        for (int ft = 0; ft < 8; ++ft) {
            float4 bv = ((const float4*)bias_n)[ft * 4 + lhi];
            float v0 = fmaxf(acc[ft][0] + bv.x, 0.f);
            float v1 = fmaxf(acc[ft][1] + bv.y, 0.f);
            float v2 = fmaxf(acc[ft][2] + bv.z, 0.f);
            float v3 = fmaxf(acc[ft][3] + bv.w, 0.f);
            uint2 pk = make_uint2((unsigned)f2b(v0) | ((unsigned)f2b(v1) << 16),
                                  (unsigned)f2b(v2) | ((unsigned)f2b(v3) << 16));
            if (nglob < N_NODES)
                *(uint2*)(yh + ((size_t)ft * N_NODES + nglob) * 16 + fsub) = pk;
        }
    }
}

// ---------------- segment max, XCD-pinned slices, 4-node ILP ----------------
__global__ __launch_bounds__(256) void seg_max_kernel(
    const unsigned short* __restrict__ hs, const int* __restrict__ row_ptr,
    const int* __restrict__ edge_src, unsigned short* __restrict__ pooled) {
    const int s = blockIdx.x & 7;
    const int g = blockIdx.x >> 3;            // node group of 16
    const int wv = threadIdx.x >> 6;
    const int lane = threadIdx.x & 63;
    const int qn = lane >> 4;                 // node-in-wave 0..3
    const int slot = (lane >> 2) & 3;         // edge slot 0..3
    const int f = lane & 3;                   // feat quad 0..3
    int node = g * 16 + wv * 4 + qn;
    const bool valid = node < N_NODES;
    node = valid ? node : N_NODES - 1;
    const unsigned short* hbase = hs + (size_t)s * N_NODES * 16;

    const int start = row_ptr[node];
    const int end = row_ptr[node + 1];
    unsigned int a0 = 0u, a1 = 0u;            // packed 4x bf16 (>=0)
    int i = start + slot;
    for (; i + 4 < end; i += 8) {
        const uint2 v0 = *(const uint2*)(hbase + (size_t)edge_src[i] * 16 + f * 4);
        const uint2 v1 = *(const uint2*)(hbase + (size_t)edge_src[i + 4] * 16 + f * 4);
        a0 = pkmax(a0, v0.x); a1 = pkmax(a1, v0.y);
        a0 = pkmax(a0, v1.x); a1 = pkmax(a1, v1.y);
    }
    if (i < end) {
        const uint2 v0 = *(const uint2*)(hbase + (size_t)edge_src[i] * 16 + f * 4);
        a0 = pkmax(a0, v0.x); a1 = pkmax(a1, v0.y);
    }
    a0 = pkmax(a0, __shfl_xor(a0, 4, 64));
    a1 = pkmax(a1, __shfl_xor(a1, 4, 64));
    a0 = pkmax(a0, __shfl_xor(a0, 8, 64));
    a1 = pkmax(a1, __shfl_xor(a1, 8, 64));
    if (slot == 0 && valid) {
        *(uint2*)(pooled + ((size_t)s * N_NODES + node) * 16 + f * 4) = make_uint2(a0, a1);
    }
}

// ---------------- launch ----------------
// ws (~148 MB < proven 161): edge_src 6.4 | ebuf 12.8 | deg 0.4 | bkt_cnt 1K |
// row_ptr 0.4 | blk_sums 2K | bkt_start 1K | bkt_cursor 1K | wt 0.39 |
// bufH 25.6 (slice-major) | bufP 25.6 (slice-major) | bufX0 25.6 | bufX1 25.6
// x chain: feats(f32) -> X0 -> X1 -> X0 -> d_out(f32)

extern "C" void kernel_launch(void* const* d_in, const int* in_sizes, int n_in,
                              void* d_out, int out_size, void* d_ws, size_t ws_size,
                              hipStream_t stream) {
    const float* feats = (const float*)d_in[0];
    const float* Wp = (const float*)d_in[1];
    const float* bp = (const float*)d_in[2];
    const float* Ws = (const float*)d_in[3];
    const float* Wn = (const float*)d_in[4];
    const float* bb = (const float*)d_in[5];
    const int* src = (const int*)d_in[6];
    const int* dst = (const int*)d_in[7];
    float* out = (float*)d_out;

    const size_t NF = (size_t)N_NODES * FEAT;
    char* ws = (char*)d_ws;
    int* edge_src = (int*)ws;    ws += (size_t)N_EDGES * sizeof(int);
    int2* ebuf = (int2*)ws;      ws += (size_t)N_EDGES * sizeof(int2);
    int* deg = (int*)ws;         ws += (size_t)N_NODES * sizeof(int);
    int* bkt_cnt = (int*)ws;     ws += 256 * sizeof(int);
    int* row_ptr = (int*)ws;     ws += (size_t)(N_NODES + 4) * sizeof(int);
    int* blk_sums = (int*)ws;    ws += 512 * sizeof(int);
    int* bkt_start = (int*)ws;   ws += 256 * sizeof(int);
    int* bkt_cursor = (int*)ws;  ws += 256 * sizeof(int);
    unsigned short* wt = (unsigned short*)ws;    ws += (size_t)12 * 16384 * sizeof(unsigned short);
    unsigned short* bufH = (unsigned short*)ws;  ws += NF * sizeof(unsigned short);
    unsigned short* bufP = (unsigned short*)ws;  ws += NF * sizeof(unsigned short);
    unsigned short* bufX0 = (unsigned short*)ws; ws += NF * sizeof(unsigned short);
    unsigned short* bufX1 = (unsigned short*)ws;

    // CSR build (deg & bkt_cnt adjacent -> single memset)
    hipMemsetAsync(deg, 0, ((size_t)N_NODES + 256) * sizeof(int), stream);
    count_deg_kernel<<<N_P1_BLKS, 256, 0, stream>>>(dst, deg, bkt_cnt);
    blk_sum_kernel<<<N_SCAN_BLKS, SCAN_BLK, 0, stream>>>(deg, blk_sums);
    scan_all_kernel<<<1, 512, 0, stream>>>(blk_sums, bkt_cnt, bkt_start, bkt_cursor);
    write_rowptr_kernel<<<N_SCAN_BLKS, SCAN_BLK, 0, stream>>>(deg, blk_sums, row_ptr);
    bucket_scatter_kernel<<<N_P1_BLKS, 256, 0, stream>>>(src, dst, bkt_cursor, ebuf);
    csr_scatter_kernel<<<NBKT, 256, 0, stream>>>(ebuf, bkt_start, row_ptr, edge_src);
    convert_wt_kernel<<<48, 256, 0, stream>>>(Wp, Ws, Wn, wt);

    const int seg_grid = ((N_NODES + 15) / 16) * 8;   // 6250 groups x 8 slices

    const unsigned short* xb[LAYERS] = {nullptr, bufX0, bufX1, bufX0};
    unsigned short* xo[LAYERS] = {bufX0, bufX1, bufX0, nullptr};

    // layer 0 h_pool
    gemm_kernel<0, true><<<GEMM_GRID, 256, 0, stream>>>(
        feats, nullptr, wt, nullptr, bp, nullptr, nullptr, nullptr, nullptr, bufH);

    for (int l = 0; l < LAYERS; ++l) {
        const unsigned short* WsT = wt + (size_t)(4 + l) * 16384;
        const unsigned short* WnT = wt + (size_t)(8 + l) * 16384;
        const float* bl = bb + (size_t)l * FEAT;

        seg_max_kernel<<<seg_grid, 256, 0, stream>>>(bufH, row_ptr, edge_src, bufP);

        if (l == 0) {
            gemm_kernel<1, true><<<GEMM_GRID, 256, 0, stream>>>(
                feats, bufP, WsT, WnT, bl, wt + (size_t)(l + 1) * 16384,
                bp + (size_t)(l + 1) * FEAT, nullptr, xo[l], bufH);
        } else if (l < LAYERS - 1) {
            gemm_kernel<1, false><<<GEMM_GRID, 256, 0, stream>>>(
                xb[l], bufP, WsT, WnT, bl, wt + (size_t)(l + 1) * 16384,
                bp + (size_t)(l + 1) * FEAT, nullptr, xo[l], bufH);
        } else {
            gemm_kernel<2, false><<<GEMM_GRID, 256, 0, stream>>>(
                xb[l], bufP, WsT, WnT, bl, nullptr, nullptr, out, nullptr, nullptr);
        }
    }
}

// Round 11
// 837.278 us; speedup vs baseline: 1.1658x; 1.0261x over previous
//
#include <hip/hip_runtime.h>

#define N_NODES 100000
#define N_EDGES 1600000
#define FEAT 128
#define LAYERS 4
#define SCAN_BLK 256
#define N_SCAN_BLKS ((N_NODES + SCAN_BLK - 1) / SCAN_BLK)  // 391
#define NBKT ((N_NODES + 511) >> 9)                        // 196 buckets x 512 nodes
#define P1_CHUNK 4096
#define N_P1_BLKS ((N_EDGES + P1_CHUNK - 1) / P1_CHUNK)    // 391
#define GEMM_GRID ((N_NODES + 63) / 64)                    // 1563

typedef __attribute__((ext_vector_type(8))) short bf16x8;
typedef __attribute__((ext_vector_type(4))) float f32x4;

__device__ __forceinline__ unsigned short f2b(float f) {   // f32 -> bf16 RNE
    union { float f; unsigned int u; } v; v.f = f;
    unsigned int u = v.u;
    return (unsigned short)((u + 0x7fffu + ((u >> 16) & 1u)) >> 16);
}

// packed max of 2x bf16 (valid for non-negative bf16: bit pattern is monotone)
__device__ __forceinline__ unsigned int pkmax(unsigned int a, unsigned int b) {
    unsigned int r;
    asm("v_pk_max_u16 %0, %1, %2" : "=v"(r) : "v"(a), "v"(b));
    return r;
}

// ---------------- CSR build (bucketed) ----------------

__global__ __launch_bounds__(256) void count_deg_kernel(const int* __restrict__ dst,
                                                        int* __restrict__ deg,
                                                        int* __restrict__ bkt_cnt) {
    __shared__ int h[NBKT];
    for (int i = threadIdx.x; i < NBKT; i += 256) h[i] = 0;
    __syncthreads();
    const int base = blockIdx.x * P1_CHUNK;
    for (int i = threadIdx.x; i < P1_CHUNK; i += 256) {
        int e = base + i;
        if (e < N_EDGES) {
            int d = dst[e];
            atomicAdd(&deg[d], 1);
            atomicAdd(&h[d >> 9], 1);
        }
    }
    __syncthreads();
    for (int i = threadIdx.x; i < NBKT; i += 256)
        if (h[i]) atomicAdd(&bkt_cnt[i], h[i]);
}

__global__ __launch_bounds__(SCAN_BLK) void blk_sum_kernel(const int* __restrict__ deg,
                                                           int* __restrict__ blk_sums) {
    int i = blockIdx.x * SCAN_BLK + threadIdx.x;
    int v = (i < N_NODES) ? deg[i] : 0;
#pragma unroll
    for (int off = 32; off; off >>= 1) v += __shfl_down(v, off, 64);
    __shared__ int ws_[SCAN_BLK / 64];
    if ((threadIdx.x & 63) == 0) ws_[threadIdx.x >> 6] = v;
    __syncthreads();
    if (threadIdx.x == 0) {
        int s = 0;
#pragma unroll
        for (int w = 0; w < SCAN_BLK / 64; ++w) s += ws_[w];
        blk_sums[blockIdx.x] = s;
    }
}

__global__ __launch_bounds__(512) void scan_all_kernel(int* __restrict__ blk_sums,
                                                       const int* __restrict__ bkt_cnt,
                                                       int* __restrict__ bkt_start,
                                                       int* __restrict__ bkt_cursor) {
    __shared__ int s[512];
    __shared__ int b[256];
    const int t = threadIdx.x;
    s[t] = (t < N_SCAN_BLKS) ? blk_sums[t] : 0;
    if (t < 256) b[t] = (t < NBKT) ? bkt_cnt[t] : 0;
    __syncthreads();
    for (int off = 1; off < 512; off <<= 1) {
        int v = (t >= off) ? s[t - off] : 0;
        __syncthreads();
        s[t] += v;
        __syncthreads();
    }
    for (int off = 1; off < 256; off <<= 1) {
        int v = (t < 256 && t >= off) ? b[t - off] : 0;
        __syncthreads();
        if (t < 256) b[t] += v;
        __syncthreads();
    }
    if (t < N_SCAN_BLKS) blk_sums[t] = (t == 0) ? 0 : s[t - 1];
    if (t < NBKT) {
        int st = (t == 0) ? 0 : b[t - 1];
        bkt_start[t] = st;
        bkt_cursor[t] = st;
    }
    if (t == 0) bkt_start[NBKT] = N_EDGES;
}

__global__ __launch_bounds__(SCAN_BLK) void write_rowptr_kernel(
    const int* __restrict__ deg, const int* __restrict__ blk_off,
    int* __restrict__ row_ptr) {
    __shared__ int s[SCAN_BLK];
    const int t = threadIdx.x;
    const int i = blockIdx.x * SCAN_BLK + t;
    int v = (i < N_NODES) ? deg[i] : 0;
    s[t] = v;
    __syncthreads();
    for (int off = 1; off < SCAN_BLK; off <<= 1) {
        int u = (t >= off) ? s[t - off] : 0;
        __syncthreads();
        s[t] += u;
        __syncthreads();
    }
    int excl = s[t] - v + blk_off[blockIdx.x];
    if (i < N_NODES) row_ptr[i] = excl;
    if (i == 0) row_ptr[N_NODES] = N_EDGES;
}

__global__ __launch_bounds__(256) void bucket_scatter_kernel(
    const int* __restrict__ src, const int* __restrict__ dst,
    int* __restrict__ bkt_cursor, int2* __restrict__ ebuf) {
    __shared__ int h[NBKT], base[NBKT], cur[NBKT];
    for (int i = threadIdx.x; i < NBKT; i += 256) h[i] = 0;
    __syncthreads();
    const int b0 = blockIdx.x * P1_CHUNK;
    for (int i = threadIdx.x; i < P1_CHUNK; i += 256) {
        int e = b0 + i;
        if (e < N_EDGES) atomicAdd(&h[dst[e] >> 9], 1);
    }
    __syncthreads();
    for (int i = threadIdx.x; i < NBKT; i += 256) {
        cur[i] = 0;
        base[i] = h[i] ? atomicAdd(&bkt_cursor[i], h[i]) : 0;
    }
    __syncthreads();
    for (int i = threadIdx.x; i < P1_CHUNK; i += 256) {
        int e = b0 + i;
        if (e < N_EDGES) {
            int d = dst[e];
            int bk = d >> 9;
            int pos = base[bk] + atomicAdd(&cur[bk], 1);
            ebuf[pos] = make_int2(src[e], d);
        }
    }
}

__global__ __launch_bounds__(256) void csr_scatter_kernel(
    const int2* __restrict__ ebuf, const int* __restrict__ bkt_start,
    const int* __restrict__ row_ptr, int* __restrict__ edge_src) {
    __shared__ int cur[512];
    const int bk = blockIdx.x;
    const int n0 = bk << 9;
    for (int i = threadIdx.x; i < 512; i += 256) {
        int n = n0 + i;
        cur[i] = (n < N_NODES) ? row_ptr[n] : 0;
    }
    __syncthreads();
    const int s = bkt_start[bk], e = bkt_start[bk + 1];
    for (int i = s + threadIdx.x; i < e; i += 256) {
        int2 ed = ebuf[i];
        int pos = atomicAdd(&cur[ed.y - n0], 1);
        edge_src[pos] = ed.x;
    }
}

// ---------------- weight convert: Wt[m][n][k] = bf16(W[m][k][n]) ----------------
__global__ __launch_bounds__(256) void convert_wt_kernel(
    const float* __restrict__ Wp, const float* __restrict__ Ws,
    const float* __restrict__ Wn, unsigned short* __restrict__ wt) {
    __shared__ float tile[64][65];
    const int m = blockIdx.x >> 2;
    const int tij = blockIdx.x & 3;
    const int ti = tij >> 1, tj = tij & 1;
    const float* W = (m < 4) ? Wp + (size_t)m * 16384
                   : (m < 8) ? Ws + (size_t)(m - 4) * 16384
                             : Wn + (size_t)(m - 8) * 16384;
#pragma unroll
    for (int i = 0; i < 16; ++i) {
        int e = i * 256 + threadIdx.x;
        int r = e >> 6, c = e & 63;
        tile[r][c] = W[(size_t)(ti * 64 + r) * 128 + tj * 64 + c];
    }
    __syncthreads();
#pragma unroll
    for (int i = 0; i < 16; ++i) {
        int e = i * 256 + threadIdx.x;
        int r = e >> 6, c = e & 63;
        wt[(size_t)m * 16384 + (size_t)(tj * 64 + r) * 128 + ti * 64 + c] = f2b(tile[c][r]);
    }
}

// ---------------- MFMA GEMM: NO LDS STAGING, NO BARRIERS ----------------
// Swapped operands: D col=lane&15 -> NODE (nrow), D row=4*(lane>>4)+reg -> feats.
// Lane's x/p fragments are ITS OWN NODE'S row -> load DIRECTLY global->VGPR:
// per (ft,kk) a wave touches 16 rows x 64B-aligned chunks (every line once).
// W streamed from L2/L1 (all waves in all blocks read identical addresses).
// Only LDS: 16KB wave-private x' exchange band for pass 3 (same-wave wr->rd,
// compiler orders via lgkmcnt; no cross-wave use -> zero __syncthreads).
// MODE 0: h  = bf16(relu(x@W1+bias))           -> yh SLICE-MAJOR [ft][n][16]
// MODE 1: x' = relu(x@W1 + p@W2 + bias)        -> yx bf16 row-major
//         h' = bf16(relu(x'@Wnt + bias_n))     -> yh SLICE-MAJOR
// MODE 2: x' -> yf f32 row-major (final out)
// p input is SLICE-MAJOR [s][n][16].
template <int MODE, bool AF32>
__global__ __launch_bounds__(256, 4) void gemm_kernel(
    const void* __restrict__ xv, const unsigned short* __restrict__ p,
    const unsigned short* __restrict__ W1t, const unsigned short* __restrict__ W2t,
    const float* __restrict__ bias,
    const unsigned short* __restrict__ Wnt, const float* __restrict__ bias_n,
    float* __restrict__ yf, unsigned short* __restrict__ yx,
    unsigned short* __restrict__ yh) {
    __shared__ unsigned short xs[64 * FEAT];  // x' exchange only (MODE 1)
    const int tid = threadIdx.x;
    const int wv = tid >> 6;
    const int lane = tid & 63;
    const int l15 = lane & 15;
    const int lhi = lane >> 4;
    const int n0 = blockIdx.x * 64;
    const int nrow = 16 * wv + l15;     // node-in-tile this lane owns
    const int nglob = n0 + nrow;
    const int nclamp = (nglob < N_NODES) ? nglob : (N_NODES - 1);
    const int fsub = 4 * lhi;

    // ---- direct global->VGPR fragment loads (all independent, all in flight) --
    bf16x8 xf[4];
    if (AF32) {
        const float* x = (const float*)xv;
#pragma unroll
        for (int kk = 0; kk < 4; ++kk) {
            const float4* g = (const float4*)(x + (size_t)nclamp * FEAT + kk * 32 + lhi * 8);
            float4 v0 = g[0], v1 = g[1];
            unsigned short hh[8];
            hh[0] = f2b(v0.x); hh[1] = f2b(v0.y); hh[2] = f2b(v0.z); hh[3] = f2b(v0.w);
            hh[4] = f2b(v1.x); hh[5] = f2b(v1.y); hh[6] = f2b(v1.z); hh[7] = f2b(v1.w);
            xf[kk] = *(bf16x8*)hh;
        }
    } else {
        const unsigned short* xb = (const unsigned short*)xv;
#pragma unroll
        for (int kk = 0; kk < 4; ++kk)
            xf[kk] = *(const bf16x8*)(xb + (size_t)nclamp * FEAT + kk * 32 + lhi * 8);
    }
    bf16x8 pf[4];
    if (MODE >= 1) {
#pragma unroll
        for (int kk = 0; kk < 4; ++kk) {
            int f0 = kk * 32 + lhi * 8;            // first feature of this frag
            int sl = f0 >> 4;                      // slice
            int off = f0 & 15;                     // 0 or 8
            pf[kk] = *(const bf16x8*)(p + ((size_t)sl * N_NODES + nclamp) * 16 + off);
        }
    }

    f32x4 acc[8];
#pragma unroll
    for (int q = 0; q < 8; ++q) acc[q] = (f32x4)(0.f);

#pragma unroll
    for (int ft = 0; ft < 8; ++ft) {
        const unsigned short* wrow = W1t + (size_t)(ft * 16 + l15) * FEAT;
#pragma unroll
        for (int kk = 0; kk < 4; ++kk) {
            bf16x8 wfrag = *(const bf16x8*)(wrow + kk * 32 + lhi * 8);
            acc[ft] = __builtin_amdgcn_mfma_f32_16x16x32_bf16(wfrag, xf[kk], acc[ft], 0, 0, 0);
        }
    }
    if (MODE >= 1) {
#pragma unroll
        for (int ft = 0; ft < 8; ++ft) {
            const unsigned short* wrow = W2t + (size_t)(ft * 16 + l15) * FEAT;
#pragma unroll
            for (int kk = 0; kk < 4; ++kk) {
                bf16x8 wfrag = *(const bf16x8*)(wrow + kk * 32 + lhi * 8);
                acc[ft] = __builtin_amdgcn_mfma_f32_16x16x32_bf16(wfrag, pf[kk], acc[ft], 0, 0, 0);
            }
        }
    }

    // ---- epilogue 1: bias + relu; wide stores; x' into wave-private LDS band --
#pragma unroll
    for (int ft = 0; ft < 8; ++ft) {
        float4 bv = ((const float4*)bias)[ft * 4 + lhi];
        float v0 = fmaxf(acc[ft][0] + bv.x, 0.f);
        float v1 = fmaxf(acc[ft][1] + bv.y, 0.f);
        float v2 = fmaxf(acc[ft][2] + bv.z, 0.f);
        float v3 = fmaxf(acc[ft][3] + bv.w, 0.f);
        uint2 pk = make_uint2((unsigned)f2b(v0) | ((unsigned)f2b(v1) << 16),
                              (unsigned)f2b(v2) | ((unsigned)f2b(v3) << 16));
        if (MODE == 0) {
            if (nglob < N_NODES)
                *(uint2*)(yh + ((size_t)ft * N_NODES + nglob) * 16 + fsub) = pk;
        } else if (MODE == 2) {
            if (nglob < N_NODES)
                *(float4*)(yf + (size_t)nglob * FEAT + ft * 16 + fsub) =
                    make_float4(v0, v1, v2, v3);
        } else {
            if (nglob < N_NODES)
                *(uint2*)(yx + (size_t)nglob * FEAT + ft * 16 + fsub) = pk;
            int byte = (nrow * 256 + (ft * 16 + fsub) * 2) ^ ((nrow & 7) << 4);
            *(uint2*)((char*)xs + byte) = pk;   // own band only
        }
    }

    // ---- pass 3 (MODE 1): h' = relu(x' @ Wnt + bias_n) -> slice-major ----
    if (MODE == 1) {
        bf16x8 xf2[4];
#pragma unroll
        for (int kk = 0; kk < 4; ++kk) {
            int byte = (nrow * 256 + (kk * 32 + lhi * 8) * 2) ^ ((nrow & 7) << 4);
            xf2[kk] = *(const bf16x8*)((const char*)xs + byte);
        }
#pragma unroll
        for (int q = 0; q < 8; ++q) acc[q] = (f32x4)(0.f);
#pragma unroll
        for (int ft = 0; ft < 8; ++ft) {
            const unsigned short* wrow = Wnt + (size_t)(ft * 16 + l15) * FEAT;
#pragma unroll
            for (int kk = 0; kk < 4; ++kk) {
                bf16x8 wfrag = *(const bf16x8*)(wrow + kk * 32 + lhi * 8);
                acc[ft] = __builtin_amdgcn_mfma_f32_16x16x32_bf16(wfrag, xf2[kk], acc[ft], 0, 0, 0);
            }
        }
#pragma unroll
        for (int ft = 0; ft < 8; ++ft) {
            float4 bv = ((const float4*)bias_n)[ft * 4 + lhi];
            float v0 = fmaxf(acc[ft][0] + bv.x, 0.f);
            float v1 = fmaxf(acc[ft][1] + bv.y, 0.f);
            float v2 = fmaxf(acc[ft][2] + bv.z, 0.f);
            float v3 = fmaxf(acc[ft][3] + bv.w, 0.f);
            uint2 pk = make_uint2((unsigned)f2b(v0) | ((unsigned)f2b(v1) << 16),
                                  (unsigned)f2b(v2) | ((unsigned)f2b(v3) << 16));
            if (nglob < N_NODES)
                *(uint2*)(yh + ((size_t)ft * N_NODES + nglob) * 16 + fsub) = pk;
        }
    }
}

// ---------------- segment max, XCD-pinned slices, 4-node ILP ----------------
__global__ __launch_bounds__(256) void seg_max_kernel(
    const unsigned short* __restrict__ hs, const int* __restrict__ row_ptr,
    const int* __restrict__ edge_src, unsigned short* __restrict__ pooled) {
    const int s = blockIdx.x & 7;
    const int g = blockIdx.x >> 3;            // node group of 16
    const int wv = threadIdx.x >> 6;
    const int lane = threadIdx.x & 63;
    const int qn = lane >> 4;                 // node-in-wave 0..3
    const int slot = (lane >> 2) & 3;         // edge slot 0..3
    const int f = lane & 3;                   // feat quad 0..3
    int node = g * 16 + wv * 4 + qn;
    const bool valid = node < N_NODES;
    node = valid ? node : N_NODES - 1;
    const unsigned short* hbase = hs + (size_t)s * N_NODES * 16;

    const int start = row_ptr[node];
    const int end = row_ptr[node + 1];
    unsigned int a0 = 0u, a1 = 0u;            // packed 4x bf16 (>=0)
    int i = start + slot;
    for (; i + 4 < end; i += 8) {
        const uint2 v0 = *(const uint2*)(hbase + (size_t)edge_src[i] * 16 + f * 4);
        const uint2 v1 = *(const uint2*)(hbase + (size_t)edge_src[i + 4] * 16 + f * 4);
        a0 = pkmax(a0, v0.x); a1 = pkmax(a1, v0.y);
        a0 = pkmax(a0, v1.x); a1 = pkmax(a1, v1.y);
    }
    if (i < end) {
        const uint2 v0 = *(const uint2*)(hbase + (size_t)edge_src[i] * 16 + f * 4);
        a0 = pkmax(a0, v0.x); a1 = pkmax(a1, v0.y);
    }
    a0 = pkmax(a0, __shfl_xor(a0, 4, 64));
    a1 = pkmax(a1, __shfl_xor(a1, 4, 64));
    a0 = pkmax(a0, __shfl_xor(a0, 8, 64));
    a1 = pkmax(a1, __shfl_xor(a1, 8, 64));
    if (slot == 0 && valid) {
        *(uint2*)(pooled + ((size_t)s * N_NODES + node) * 16 + f * 4) = make_uint2(a0, a1);
    }
}

// ---------------- launch ----------------
// ws (~148 MB < proven 161): edge_src 6.4 | ebuf 12.8 | deg 0.4 | bkt_cnt 1K |
// row_ptr 0.4 | blk_sums 2K | bkt_start 1K | bkt_cursor 1K | wt 0.39 |
// bufH 25.6 (slice-major) | bufP 25.6 (slice-major) | bufX0 25.6 | bufX1 25.6
// x chain: feats(f32) -> X0 -> X1 -> X0 -> d_out(f32)

extern "C" void kernel_launch(void* const* d_in, const int* in_sizes, int n_in,
                              void* d_out, int out_size, void* d_ws, size_t ws_size,
                              hipStream_t stream) {
    const float* feats = (const float*)d_in[0];
    const float* Wp = (const float*)d_in[1];
    const float* bp = (const float*)d_in[2];
    const float* Ws = (const float*)d_in[3];
    const float* Wn = (const float*)d_in[4];
    const float* bb = (const float*)d_in[5];
    const int* src = (const int*)d_in[6];
    const int* dst = (const int*)d_in[7];
    float* out = (float*)d_out;

    const size_t NF = (size_t)N_NODES * FEAT;
    char* ws = (char*)d_ws;
    int* edge_src = (int*)ws;    ws += (size_t)N_EDGES * sizeof(int);
    int2* ebuf = (int2*)ws;      ws += (size_t)N_EDGES * sizeof(int2);
    int* deg = (int*)ws;         ws += (size_t)N_NODES * sizeof(int);
    int* bkt_cnt = (int*)ws;     ws += 256 * sizeof(int);
    int* row_ptr = (int*)ws;     ws += (size_t)(N_NODES + 4) * sizeof(int);
    int* blk_sums = (int*)ws;    ws += 512 * sizeof(int);
    int* bkt_start = (int*)ws;   ws += 256 * sizeof(int);
    int* bkt_cursor = (int*)ws;  ws += 256 * sizeof(int);
    unsigned short* wt = (unsigned short*)ws;    ws += (size_t)12 * 16384 * sizeof(unsigned short);
    unsigned short* bufH = (unsigned short*)ws;  ws += NF * sizeof(unsigned short);
    unsigned short* bufP = (unsigned short*)ws;  ws += NF * sizeof(unsigned short);
    unsigned short* bufX0 = (unsigned short*)ws; ws += NF * sizeof(unsigned short);
    unsigned short* bufX1 = (unsigned short*)ws;

    // CSR build (deg & bkt_cnt adjacent -> single memset)
    hipMemsetAsync(deg, 0, ((size_t)N_NODES + 256) * sizeof(int), stream);
    count_deg_kernel<<<N_P1_BLKS, 256, 0, stream>>>(dst, deg, bkt_cnt);
    blk_sum_kernel<<<N_SCAN_BLKS, SCAN_BLK, 0, stream>>>(deg, blk_sums);
    scan_all_kernel<<<1, 512, 0, stream>>>(blk_sums, bkt_cnt, bkt_start, bkt_cursor);
    write_rowptr_kernel<<<N_SCAN_BLKS, SCAN_BLK, 0, stream>>>(deg, blk_sums, row_ptr);
    bucket_scatter_kernel<<<N_P1_BLKS, 256, 0, stream>>>(src, dst, bkt_cursor, ebuf);
    csr_scatter_kernel<<<NBKT, 256, 0, stream>>>(ebuf, bkt_start, row_ptr, edge_src);
    convert_wt_kernel<<<48, 256, 0, stream>>>(Wp, Ws, Wn, wt);

    const int seg_grid = ((N_NODES + 15) / 16) * 8;   // 6250 groups x 8 slices

    const unsigned short* xb[LAYERS] = {nullptr, bufX0, bufX1, bufX0};
    unsigned short* xo[LAYERS] = {bufX0, bufX1, bufX0, nullptr};

    // layer 0 h_pool
    gemm_kernel<0, true><<<GEMM_GRID, 256, 0, stream>>>(
        feats, nullptr, wt, nullptr, bp, nullptr, nullptr, nullptr, nullptr, bufH);

    for (int l = 0; l < LAYERS; ++l) {
        const unsigned short* WsT = wt + (size_t)(4 + l) * 16384;
        const unsigned short* WnT = wt + (size_t)(8 + l) * 16384;
        const float* bl = bb + (size_t)l * FEAT;

        seg_max_kernel<<<seg_grid, 256, 0, stream>>>(bufH, row_ptr, edge_src, bufP);

        if (l == 0) {
            gemm_kernel<1, true><<<GEMM_GRID, 256, 0, stream>>>(
                feats, bufP, WsT, WnT, bl, wt + (size_t)(l + 1) * 16384,
                bp + (size_t)(l + 1) * FEAT, nullptr, xo[l], bufH);
        } else if (l < LAYERS - 1) {
            gemm_kernel<1, false><<<GEMM_GRID, 256, 0, stream>>>(
                xb[l], bufP, WsT, WnT, bl, wt + (size_t)(l + 1) * 16384,
                bp + (size_t)(l + 1) * FEAT, nullptr, xo[l], bufH);
        } else {
            gemm_kernel<2, false><<<GEMM_GRID, 256, 0, stream>>>(
                xb[l], bufP, WsT, WnT, bl, nullptr, nullptr, out, nullptr, nullptr);
        }
    }
}

// Round 12
// 734.507 us; speedup vs baseline: 1.3289x; 1.1399x over previous
//
#include <hip/hip_runtime.h>

#define N_NODES 100000
#define N_EDGES 1600000
#define FEAT 128
#define LAYERS 4
#define SCAN_BLK 256
#define N_SCAN_BLKS ((N_NODES + SCAN_BLK - 1) / SCAN_BLK)  // 391
#define NBKT ((N_NODES + 511) >> 9)                        // 196 buckets x 512 nodes
#define P1_CHUNK 4096
#define N_P1_BLKS ((N_EDGES + P1_CHUNK - 1) / P1_CHUNK)    // 391
#define GEMM_GRID ((N_NODES + 127) / 128)                  // 782 (128 nodes/block)

typedef __attribute__((ext_vector_type(8))) short bf16x8;
typedef __attribute__((ext_vector_type(4))) float f32x4;

__device__ __forceinline__ unsigned short f2b(float f) {   // f32 -> bf16 RNE
    union { float f; unsigned int u; } v; v.f = f;
    unsigned int u = v.u;
    return (unsigned short)((u + 0x7fffu + ((u >> 16) & 1u)) >> 16);
}

// packed max of 2x bf16 (valid for non-negative bf16: bit pattern is monotone)
__device__ __forceinline__ unsigned int pkmax(unsigned int a, unsigned int b) {
    unsigned int r;
    asm("v_pk_max_u16 %0, %1, %2" : "=v"(r) : "v"(a), "v"(b));
    return r;
}

// ---------------- CSR build (bucketed) ----------------

__global__ __launch_bounds__(256) void count_deg_kernel(const int* __restrict__ dst,
                                                        int* __restrict__ deg,
                                                        int* __restrict__ bkt_cnt) {
    __shared__ int h[NBKT];
    for (int i = threadIdx.x; i < NBKT; i += 256) h[i] = 0;
    __syncthreads();
    const int base = blockIdx.x * P1_CHUNK;
    for (int i = threadIdx.x; i < P1_CHUNK; i += 256) {
        int e = base + i;
        if (e < N_EDGES) {
            int d = dst[e];
            atomicAdd(&deg[d], 1);
            atomicAdd(&h[d >> 9], 1);
        }
    }
    __syncthreads();
    for (int i = threadIdx.x; i < NBKT; i += 256)
        if (h[i]) atomicAdd(&bkt_cnt[i], h[i]);
}

__global__ __launch_bounds__(SCAN_BLK) void blk_sum_kernel(const int* __restrict__ deg,
                                                           int* __restrict__ blk_sums) {
    int i = blockIdx.x * SCAN_BLK + threadIdx.x;
    int v = (i < N_NODES) ? deg[i] : 0;
#pragma unroll
    for (int off = 32; off; off >>= 1) v += __shfl_down(v, off, 64);
    __shared__ int ws_[SCAN_BLK / 64];
    if ((threadIdx.x & 63) == 0) ws_[threadIdx.x >> 6] = v;
    __syncthreads();
    if (threadIdx.x == 0) {
        int s = 0;
#pragma unroll
        for (int w = 0; w < SCAN_BLK / 64; ++w) s += ws_[w];
        blk_sums[blockIdx.x] = s;
    }
}

__global__ __launch_bounds__(512) void scan_all_kernel(int* __restrict__ blk_sums,
                                                       const int* __restrict__ bkt_cnt,
                                                       int* __restrict__ bkt_start,
                                                       int* __restrict__ bkt_cursor) {
    __shared__ int s[512];
    __shared__ int b[256];
    const int t = threadIdx.x;
    s[t] = (t < N_SCAN_BLKS) ? blk_sums[t] : 0;
    if (t < 256) b[t] = (t < NBKT) ? bkt_cnt[t] : 0;
    __syncthreads();
    for (int off = 1; off < 512; off <<= 1) {
        int v = (t >= off) ? s[t - off] : 0;
        __syncthreads();
        s[t] += v;
        __syncthreads();
    }
    for (int off = 1; off < 256; off <<= 1) {
        int v = (t < 256 && t >= off) ? b[t - off] : 0;
        __syncthreads();
        if (t < 256) b[t] += v;
        __syncthreads();
    }
    if (t < N_SCAN_BLKS) blk_sums[t] = (t == 0) ? 0 : s[t - 1];
    if (t < NBKT) {
        int st = (t == 0) ? 0 : b[t - 1];
        bkt_start[t] = st;
        bkt_cursor[t] = st;
    }
    if (t == 0) bkt_start[NBKT] = N_EDGES;
}

__global__ __launch_bounds__(SCAN_BLK) void write_rowptr_kernel(
    const int* __restrict__ deg, const int* __restrict__ blk_off,
    int* __restrict__ row_ptr) {
    __shared__ int s[SCAN_BLK];
    const int t = threadIdx.x;
    const int i = blockIdx.x * SCAN_BLK + t;
    int v = (i < N_NODES) ? deg[i] : 0;
    s[t] = v;
    __syncthreads();
    for (int off = 1; off < SCAN_BLK; off <<= 1) {
        int u = (t >= off) ? s[t - off] : 0;
        __syncthreads();
        s[t] += u;
        __syncthreads();
    }
    int excl = s[t] - v + blk_off[blockIdx.x];
    if (i < N_NODES) row_ptr[i] = excl;
    if (i == 0) row_ptr[N_NODES] = N_EDGES;
}

__global__ __launch_bounds__(256) void bucket_scatter_kernel(
    const int* __restrict__ src, const int* __restrict__ dst,
    int* __restrict__ bkt_cursor, int2* __restrict__ ebuf) {
    __shared__ int h[NBKT], base[NBKT], cur[NBKT];
    for (int i = threadIdx.x; i < NBKT; i += 256) h[i] = 0;
    __syncthreads();
    const int b0 = blockIdx.x * P1_CHUNK;
    for (int i = threadIdx.x; i < P1_CHUNK; i += 256) {
        int e = b0 + i;
        if (e < N_EDGES) atomicAdd(&h[dst[e] >> 9], 1);
    }
    __syncthreads();
    for (int i = threadIdx.x; i < NBKT; i += 256) {
        cur[i] = 0;
        base[i] = h[i] ? atomicAdd(&bkt_cursor[i], h[i]) : 0;
    }
    __syncthreads();
    for (int i = threadIdx.x; i < P1_CHUNK; i += 256) {
        int e = b0 + i;
        if (e < N_EDGES) {
            int d = dst[e];
            int bk = d >> 9;
            int pos = base[bk] + atomicAdd(&cur[bk], 1);
            ebuf[pos] = make_int2(src[e], d);
        }
    }
}

__global__ __launch_bounds__(256) void csr_scatter_kernel(
    const int2* __restrict__ ebuf, const int* __restrict__ bkt_start,
    const int* __restrict__ row_ptr, int* __restrict__ edge_src) {
    __shared__ int cur[512];
    const int bk = blockIdx.x;
    const int n0 = bk << 9;
    for (int i = threadIdx.x; i < 512; i += 256) {
        int n = n0 + i;
        cur[i] = (n < N_NODES) ? row_ptr[n] : 0;
    }
    __syncthreads();
    const int s = bkt_start[bk], e = bkt_start[bk + 1];
    for (int i = s + threadIdx.x; i < e; i += 256) {
        int2 ed = ebuf[i];
        int pos = atomicAdd(&cur[ed.y - n0], 1);
        edge_src[pos] = ed.x;
    }
}

// ---------------- weight convert: Wt[m][n][k] = bf16(W[m][k][n]) ----------------
__global__ __launch_bounds__(256) void convert_wt_kernel(
    const float* __restrict__ Wp, const float* __restrict__ Ws,
    const float* __restrict__ Wn, unsigned short* __restrict__ wt) {
    __shared__ float tile[64][65];
    const int m = blockIdx.x >> 2;
    const int tij = blockIdx.x & 3;
    const int ti = tij >> 1, tj = tij & 1;
    const float* W = (m < 4) ? Wp + (size_t)m * 16384
                   : (m < 8) ? Ws + (size_t)(m - 4) * 16384
                             : Wn + (size_t)(m - 8) * 16384;
#pragma unroll
    for (int i = 0; i < 16; ++i) {
        int e = i * 256 + threadIdx.x;
        int r = e >> 6, c = e & 63;
        tile[r][c] = W[(size_t)(ti * 64 + r) * 128 + tj * 64 + c];
    }
    __syncthreads();
#pragma unroll
    for (int i = 0; i < 16; ++i) {
        int e = i * 256 + threadIdx.x;
        int r = e >> 6, c = e & 63;
        wt[(size_t)m * 16384 + (size_t)(tj * 64 + r) * 128 + ti * 64 + c] = f2b(tile[c][r]);
    }
}

// ---------------- MFMA GEMM: 2 node-groups/wave, W amortized ----------------
// Swapped operands: D col=lane&15 -> NODE, D row=4*(lane>>4)+reg -> feats.
// Wave wv owns node-groups g=0,1 at rows (2wv+g)*16+l15 -> 32 nodes/wave,
// 128 nodes/block. Each W-fragment load feeds TWO independent MFMAs.
// Direct global->VGPR x/p fragment loads; only LDS = 32KB x' exchange (MODE 1,
// wave-private band, no barriers).
// MODE 0: h  = bf16(relu(x@W1+bias))           -> yh SLICE-MAJOR [ft][n][16]
// MODE 1: x' = relu(x@W1 + p@W2 + bias)        -> yx bf16 row-major
//         h' = bf16(relu(x'@Wnt + bias_n))     -> yh SLICE-MAJOR
// MODE 2: x' -> yf f32 row-major (final out)
// p input is SLICE-MAJOR [s][n][16].
template <int MODE, bool AF32>
__global__ __launch_bounds__(256, 2) void gemm_kernel(
    const void* __restrict__ xv, const unsigned short* __restrict__ p,
    const unsigned short* __restrict__ W1t, const unsigned short* __restrict__ W2t,
    const float* __restrict__ bias,
    const unsigned short* __restrict__ Wnt, const float* __restrict__ bias_n,
    float* __restrict__ yf, unsigned short* __restrict__ yx,
    unsigned short* __restrict__ yh) {
    __shared__ unsigned short xs[128 * FEAT];  // x' exchange only (MODE 1)
    const int tid = threadIdx.x;
    const int wv = tid >> 6;
    const int lane = tid & 63;
    const int l15 = lane & 15;
    const int lhi = lane >> 4;
    const int n0 = blockIdx.x * 128;
    const int fsub = 4 * lhi;

    int nrow[2], nglob[2], nclamp[2];
#pragma unroll
    for (int g = 0; g < 2; ++g) {
        nrow[g] = (2 * wv + g) * 16 + l15;
        nglob[g] = n0 + nrow[g];
        nclamp[g] = (nglob[g] < N_NODES) ? nglob[g] : (N_NODES - 1);
    }

    // ---- direct global->VGPR fragment loads (all independent, in flight) ----
    bf16x8 xf[2][4];
    if (AF32) {
        const float* x = (const float*)xv;
#pragma unroll
        for (int g = 0; g < 2; ++g)
#pragma unroll
            for (int kk = 0; kk < 4; ++kk) {
                const float4* gp = (const float4*)(x + (size_t)nclamp[g] * FEAT + kk * 32 + lhi * 8);
                float4 v0 = gp[0], v1 = gp[1];
                unsigned short hh[8];
                hh[0] = f2b(v0.x); hh[1] = f2b(v0.y); hh[2] = f2b(v0.z); hh[3] = f2b(v0.w);
                hh[4] = f2b(v1.x); hh[5] = f2b(v1.y); hh[6] = f2b(v1.z); hh[7] = f2b(v1.w);
                xf[g][kk] = *(bf16x8*)hh;
            }
    } else {
        const unsigned short* xb = (const unsigned short*)xv;
#pragma unroll
        for (int g = 0; g < 2; ++g)
#pragma unroll
            for (int kk = 0; kk < 4; ++kk)
                xf[g][kk] = *(const bf16x8*)(xb + (size_t)nclamp[g] * FEAT + kk * 32 + lhi * 8);
    }
    bf16x8 pf[2][4];
    if (MODE >= 1) {
#pragma unroll
        for (int g = 0; g < 2; ++g)
#pragma unroll
            for (int kk = 0; kk < 4; ++kk) {
                int f0 = kk * 32 + lhi * 8;
                int sl = f0 >> 4;
                int off = f0 & 15;
                pf[g][kk] = *(const bf16x8*)(p + ((size_t)sl * N_NODES + nclamp[g]) * 16 + off);
            }
    }

    f32x4 acc[2][8];
#pragma unroll
    for (int g = 0; g < 2; ++g)
#pragma unroll
        for (int q = 0; q < 8; ++q) acc[g][q] = (f32x4)(0.f);

    // pass 1: x @ W1 (each wfrag used twice)
#pragma unroll
    for (int ft = 0; ft < 8; ++ft) {
        const unsigned short* wrow = W1t + (size_t)(ft * 16 + l15) * FEAT;
#pragma unroll
        for (int kk = 0; kk < 4; ++kk) {
            bf16x8 wfrag = *(const bf16x8*)(wrow + kk * 32 + lhi * 8);
            acc[0][ft] = __builtin_amdgcn_mfma_f32_16x16x32_bf16(wfrag, xf[0][kk], acc[0][ft], 0, 0, 0);
            acc[1][ft] = __builtin_amdgcn_mfma_f32_16x16x32_bf16(wfrag, xf[1][kk], acc[1][ft], 0, 0, 0);
        }
    }
    // pass 2: p @ W2
    if (MODE >= 1) {
#pragma unroll
        for (int ft = 0; ft < 8; ++ft) {
            const unsigned short* wrow = W2t + (size_t)(ft * 16 + l15) * FEAT;
#pragma unroll
            for (int kk = 0; kk < 4; ++kk) {
                bf16x8 wfrag = *(const bf16x8*)(wrow + kk * 32 + lhi * 8);
                acc[0][ft] = __builtin_amdgcn_mfma_f32_16x16x32_bf16(wfrag, pf[0][kk], acc[0][ft], 0, 0, 0);
                acc[1][ft] = __builtin_amdgcn_mfma_f32_16x16x32_bf16(wfrag, pf[1][kk], acc[1][ft], 0, 0, 0);
            }
        }
    }

    // ---- epilogue 1: bias + relu; wide stores; x' into wave-private LDS band --
#pragma unroll
    for (int g = 0; g < 2; ++g) {
#pragma unroll
        for (int ft = 0; ft < 8; ++ft) {
            float4 bv = ((const float4*)bias)[ft * 4 + lhi];
            float v0 = fmaxf(acc[g][ft][0] + bv.x, 0.f);
            float v1 = fmaxf(acc[g][ft][1] + bv.y, 0.f);
            float v2 = fmaxf(acc[g][ft][2] + bv.z, 0.f);
            float v3 = fmaxf(acc[g][ft][3] + bv.w, 0.f);
            uint2 pk = make_uint2((unsigned)f2b(v0) | ((unsigned)f2b(v1) << 16),
                                  (unsigned)f2b(v2) | ((unsigned)f2b(v3) << 16));
            if (MODE == 0) {
                if (nglob[g] < N_NODES)
                    *(uint2*)(yh + ((size_t)ft * N_NODES + nglob[g]) * 16 + fsub) = pk;
            } else if (MODE == 2) {
                if (nglob[g] < N_NODES)
                    *(float4*)(yf + (size_t)nglob[g] * FEAT + ft * 16 + fsub) =
                        make_float4(v0, v1, v2, v3);
            } else {
                if (nglob[g] < N_NODES)
                    *(uint2*)(yx + (size_t)nglob[g] * FEAT + ft * 16 + fsub) = pk;
                int byte = (nrow[g] * 256 + (ft * 16 + fsub) * 2) ^ ((nrow[g] & 7) << 4);
                *(uint2*)((char*)xs + byte) = pk;   // own band only
            }
        }
    }

    // ---- pass 3 (MODE 1): h' = relu(x' @ Wnt + bias_n) -> slice-major ----
    if (MODE == 1) {
        bf16x8 xf2[2][4];
#pragma unroll
        for (int g = 0; g < 2; ++g)
#pragma unroll
            for (int kk = 0; kk < 4; ++kk) {
                int byte = (nrow[g] * 256 + (kk * 32 + lhi * 8) * 2) ^ ((nrow[g] & 7) << 4);
                xf2[g][kk] = *(const bf16x8*)((const char*)xs + byte);
            }
#pragma unroll
        for (int g = 0; g < 2; ++g)
#pragma unroll
            for (int q = 0; q < 8; ++q) acc[g][q] = (f32x4)(0.f);
#pragma unroll
        for (int ft = 0; ft < 8; ++ft) {
            const unsigned short* wrow = Wnt + (size_t)(ft * 16 + l15) * FEAT;
#pragma unroll
            for (int kk = 0; kk < 4; ++kk) {
                bf16x8 wfrag = *(const bf16x8*)(wrow + kk * 32 + lhi * 8);
                acc[0][ft] = __builtin_amdgcn_mfma_f32_16x16x32_bf16(wfrag, xf2[0][kk], acc[0][ft], 0, 0, 0);
                acc[1][ft] = __builtin_amdgcn_mfma_f32_16x16x32_bf16(wfrag, xf2[1][kk], acc[1][ft], 0, 0, 0);
            }
        }
#pragma unroll
        for (int g = 0; g < 2; ++g) {
#pragma unroll
            for (int ft = 0; ft < 8; ++ft) {
                float4 bv = ((const float4*)bias_n)[ft * 4 + lhi];
                float v0 = fmaxf(acc[g][ft][0] + bv.x, 0.f);
                float v1 = fmaxf(acc[g][ft][1] + bv.y, 0.f);
                float v2 = fmaxf(acc[g][ft][2] + bv.z, 0.f);
                float v3 = fmaxf(acc[g][ft][3] + bv.w, 0.f);
                uint2 pk = make_uint2((unsigned)f2b(v0) | ((unsigned)f2b(v1) << 16),
                                      (unsigned)f2b(v2) | ((unsigned)f2b(v3) << 16));
                if (nglob[g] < N_NODES)
                    *(uint2*)(yh + ((size_t)ft * N_NODES + nglob[g]) * 16 + fsub) = pk;
            }
        }
    }
}

// ---------------- segment max, XCD-pinned slices, 4-node ILP ----------------
__global__ __launch_bounds__(256) void seg_max_kernel(
    const unsigned short* __restrict__ hs, const int* __restrict__ row_ptr,
    const int* __restrict__ edge_src, unsigned short* __restrict__ pooled) {
    const int s = blockIdx.x & 7;
    const int g = blockIdx.x >> 3;            // node group of 16
    const int wv = threadIdx.x >> 6;
    const int lane = threadIdx.x & 63;
    const int qn = lane >> 4;                 // node-in-wave 0..3
    const int slot = (lane >> 2) & 3;         // edge slot 0..3
    const int f = lane & 3;                   // feat quad 0..3
    int node = g * 16 + wv * 4 + qn;
    const bool valid = node < N_NODES;
    node = valid ? node : N_NODES - 1;
    const unsigned short* hbase = hs + (size_t)s * N_NODES * 16;

    const int start = row_ptr[node];
    const int end = row_ptr[node + 1];
    unsigned int a0 = 0u, a1 = 0u;            // packed 4x bf16 (>=0)
    int i = start + slot;
    for (; i + 4 < end; i += 8) {
        const uint2 v0 = *(const uint2*)(hbase + (size_t)edge_src[i] * 16 + f * 4);
        const uint2 v1 = *(const uint2*)(hbase + (size_t)edge_src[i + 4] * 16 + f * 4);
        a0 = pkmax(a0, v0.x); a1 = pkmax(a1, v0.y);
        a0 = pkmax(a0, v1.x); a1 = pkmax(a1, v1.y);
    }
    if (i < end) {
        const uint2 v0 = *(const uint2*)(hbase + (size_t)edge_src[i] * 16 + f * 4);
        a0 = pkmax(a0, v0.x); a1 = pkmax(a1, v0.y);
    }
    a0 = pkmax(a0, __shfl_xor(a0, 4, 64));
    a1 = pkmax(a1, __shfl_xor(a1, 4, 64));
    a0 = pkmax(a0, __shfl_xor(a0, 8, 64));
    a1 = pkmax(a1, __shfl_xor(a1, 8, 64));
    if (slot == 0 && valid) {
        *(uint2*)(pooled + ((size_t)s * N_NODES + node) * 16 + f * 4) = make_uint2(a0, a1);
    }
}

// ---------------- launch ----------------
// ws (~148 MB < proven 161): edge_src 6.4 | ebuf 12.8 | deg 0.4 | bkt_cnt 1K |
// row_ptr 0.4 | blk_sums 2K | bkt_start 1K | bkt_cursor 1K | wt 0.39 |
// bufH 25.6 (slice-major) | bufP 25.6 (slice-major) | bufX0 25.6 | bufX1 25.6
// x chain: feats(f32) -> X0 -> X1 -> X0 -> d_out(f32)

extern "C" void kernel_launch(void* const* d_in, const int* in_sizes, int n_in,
                              void* d_out, int out_size, void* d_ws, size_t ws_size,
                              hipStream_t stream) {
    const float* feats = (const float*)d_in[0];
    const float* Wp = (const float*)d_in[1];
    const float* bp = (const float*)d_in[2];
    const float* Ws = (const float*)d_in[3];
    const float* Wn = (const float*)d_in[4];
    const float* bb = (const float*)d_in[5];
    const int* src = (const int*)d_in[6];
    const int* dst = (const int*)d_in[7];
    float* out = (float*)d_out;

    const size_t NF = (size_t)N_NODES * FEAT;
    char* ws = (char*)d_ws;
    int* edge_src = (int*)ws;    ws += (size_t)N_EDGES * sizeof(int);
    int2* ebuf = (int2*)ws;      ws += (size_t)N_EDGES * sizeof(int2);
    int* deg = (int*)ws;         ws += (size_t)N_NODES * sizeof(int);
    int* bkt_cnt = (int*)ws;     ws += 256 * sizeof(int);
    int* row_ptr = (int*)ws;     ws += (size_t)(N_NODES + 4) * sizeof(int);
    int* blk_sums = (int*)ws;    ws += 512 * sizeof(int);
    int* bkt_start = (int*)ws;   ws += 256 * sizeof(int);
    int* bkt_cursor = (int*)ws;  ws += 256 * sizeof(int);
    unsigned short* wt = (unsigned short*)ws;    ws += (size_t)12 * 16384 * sizeof(unsigned short);
    unsigned short* bufH = (unsigned short*)ws;  ws += NF * sizeof(unsigned short);
    unsigned short* bufP = (unsigned short*)ws;  ws += NF * sizeof(unsigned short);
    unsigned short* bufX0 = (unsigned short*)ws; ws += NF * sizeof(unsigned short);
    unsigned short* bufX1 = (unsigned short*)ws;

    // CSR build (deg & bkt_cnt adjacent -> single memset)
    hipMemsetAsync(deg, 0, ((size_t)N_NODES + 256) * sizeof(int), stream);
    count_deg_kernel<<<N_P1_BLKS, 256, 0, stream>>>(dst, deg, bkt_cnt);
    blk_sum_kernel<<<N_SCAN_BLKS, SCAN_BLK, 0, stream>>>(deg, blk_sums);
    scan_all_kernel<<<1, 512, 0, stream>>>(blk_sums, bkt_cnt, bkt_start, bkt_cursor);
    write_rowptr_kernel<<<N_SCAN_BLKS, SCAN_BLK, 0, stream>>>(deg, blk_sums, row_ptr);
    bucket_scatter_kernel<<<N_P1_BLKS, 256, 0, stream>>>(src, dst, bkt_cursor, ebuf);
    csr_scatter_kernel<<<NBKT, 256, 0, stream>>>(ebuf, bkt_start, row_ptr, edge_src);
    convert_wt_kernel<<<48, 256, 0, stream>>>(Wp, Ws, Wn, wt);

    const int seg_grid = ((N_NODES + 15) / 16) * 8;   // 6250 groups x 8 slices

    const unsigned short* xb[LAYERS] = {nullptr, bufX0, bufX1, bufX0};
    unsigned short* xo[LAYERS] = {bufX0, bufX1, bufX0, nullptr};

    // layer 0 h_pool
    gemm_kernel<0, true><<<GEMM_GRID, 256, 0, stream>>>(
        feats, nullptr, wt, nullptr, bp, nullptr, nullptr, nullptr, nullptr, bufH);

    for (int l = 0; l < LAYERS; ++l) {
        const unsigned short* WsT = wt + (size_t)(4 + l) * 16384;
        const unsigned short* WnT = wt + (size_t)(8 + l) * 16384;
        const float* bl = bb + (size_t)l * FEAT;

        seg_max_kernel<<<seg_grid, 256, 0, stream>>>(bufH, row_ptr, edge_src, bufP);

        if (l == 0) {
            gemm_kernel<1, true><<<GEMM_GRID, 256, 0, stream>>>(
                feats, bufP, WsT, WnT, bl, wt + (size_t)(l + 1) * 16384,
                bp + (size_t)(l + 1) * FEAT, nullptr, xo[l], bufH);
        } else if (l < LAYERS - 1) {
            gemm_kernel<1, false><<<GEMM_GRID, 256, 0, stream>>>(
                xb[l], bufP, WsT, WnT, bl, wt + (size_t)(l + 1) * 16384,
                bp + (size_t)(l + 1) * FEAT, nullptr, xo[l], bufH);
        } else {
            gemm_kernel<2, false><<<GEMM_GRID, 256, 0, stream>>>(
                xb[l], bufP, WsT, WnT, bl, nullptr, nullptr, out, nullptr, nullptr);
        }
    }
}

// Round 13
// 714.721 us; speedup vs baseline: 1.3657x; 1.0277x over previous
//
#include <hip/hip_runtime.h>

#define N_NODES 100000
#define N_EDGES 1600000
#define FEAT 128
#define LAYERS 4
#define SCAN_BLK 256
#define N_SCAN_BLKS ((N_NODES + SCAN_BLK - 1) / SCAN_BLK)  // 391
#define NBKT ((N_NODES + 511) >> 9)                        // 196 buckets x 512 nodes
#define P1_CHUNK 4096
#define N_P1_BLKS ((N_EDGES + P1_CHUNK - 1) / P1_CHUNK)    // 391
#define GEMM_GRID ((N_NODES + 127) / 128)                  // 782 (128 nodes/block)

typedef __attribute__((ext_vector_type(8))) short bf16x8;
typedef __attribute__((ext_vector_type(4))) float f32x4;

__device__ __forceinline__ unsigned short f2b(float f) {   // f32 -> bf16 RNE
    union { float f; unsigned int u; } v; v.f = f;
    unsigned int u = v.u;
    return (unsigned short)((u + 0x7fffu + ((u >> 16) & 1u)) >> 16);
}

// packed max of 2x bf16 (valid for non-negative bf16: bit pattern is monotone)
__device__ __forceinline__ unsigned int pkmax(unsigned int a, unsigned int b) {
    unsigned int r;
    asm("v_pk_max_u16 %0, %1, %2" : "=v"(r) : "v"(a), "v"(b));
    return r;
}

// ---------------- CSR build (bucketed) ----------------

__global__ __launch_bounds__(256) void count_deg_kernel(const int* __restrict__ dst,
                                                        int* __restrict__ deg,
                                                        int* __restrict__ bkt_cnt) {
    __shared__ int h[NBKT];
    for (int i = threadIdx.x; i < NBKT; i += 256) h[i] = 0;
    __syncthreads();
    const int base = blockIdx.x * P1_CHUNK;
    for (int i = threadIdx.x; i < P1_CHUNK; i += 256) {
        int e = base + i;
        if (e < N_EDGES) {
            int d = dst[e];
            atomicAdd(&deg[d], 1);
            atomicAdd(&h[d >> 9], 1);
        }
    }
    __syncthreads();
    for (int i = threadIdx.x; i < NBKT; i += 256)
        if (h[i]) atomicAdd(&bkt_cnt[i], h[i]);
}

__global__ __launch_bounds__(SCAN_BLK) void blk_sum_kernel(const int* __restrict__ deg,
                                                           int* __restrict__ blk_sums) {
    int i = blockIdx.x * SCAN_BLK + threadIdx.x;
    int v = (i < N_NODES) ? deg[i] : 0;
#pragma unroll
    for (int off = 32; off; off >>= 1) v += __shfl_down(v, off, 64);
    __shared__ int ws_[SCAN_BLK / 64];
    if ((threadIdx.x & 63) == 0) ws_[threadIdx.x >> 6] = v;
    __syncthreads();
    if (threadIdx.x == 0) {
        int s = 0;
#pragma unroll
        for (int w = 0; w < SCAN_BLK / 64; ++w) s += ws_[w];
        blk_sums[blockIdx.x] = s;
    }
}

__global__ __launch_bounds__(512) void scan_all_kernel(int* __restrict__ blk_sums,
                                                       const int* __restrict__ bkt_cnt,
                                                       int* __restrict__ bkt_start,
                                                       int* __restrict__ bkt_cursor) {
    __shared__ int s[512];
    __shared__ int b[256];
    const int t = threadIdx.x;
    s[t] = (t < N_SCAN_BLKS) ? blk_sums[t] : 0;
    if (t < 256) b[t] = (t < NBKT) ? bkt_cnt[t] : 0;
    __syncthreads();
    for (int off = 1; off < 512; off <<= 1) {
        int v = (t >= off) ? s[t - off] : 0;
        __syncthreads();
        s[t] += v;
        __syncthreads();
    }
    for (int off = 1; off < 256; off <<= 1) {
        int v = (t < 256 && t >= off) ? b[t - off] : 0;
        __syncthreads();
        if (t < 256) b[t] += v;
        __syncthreads();
    }
    if (t < N_SCAN_BLKS) blk_sums[t] = (t == 0) ? 0 : s[t - 1];
    if (t < NBKT) {
        int st = (t == 0) ? 0 : b[t - 1];
        bkt_start[t] = st;
        bkt_cursor[t] = st;
    }
    if (t == 0) bkt_start[NBKT] = N_EDGES;
}

__global__ __launch_bounds__(SCAN_BLK) void write_rowptr_kernel(
    const int* __restrict__ deg, const int* __restrict__ blk_off,
    int* __restrict__ row_ptr) {
    __shared__ int s[SCAN_BLK];
    const int t = threadIdx.x;
    const int i = blockIdx.x * SCAN_BLK + t;
    int v = (i < N_NODES) ? deg[i] : 0;
    s[t] = v;
    __syncthreads();
    for (int off = 1; off < SCAN_BLK; off <<= 1) {
        int u = (t >= off) ? s[t - off] : 0;
        __syncthreads();
        s[t] += u;
        __syncthreads();
    }
    int excl = s[t] - v + blk_off[blockIdx.x];
    if (i < N_NODES) row_ptr[i] = excl;
    if (i == 0) row_ptr[N_NODES] = N_EDGES;
}

__global__ __launch_bounds__(256) void bucket_scatter_kernel(
    const int* __restrict__ src, const int* __restrict__ dst,
    int* __restrict__ bkt_cursor, int2* __restrict__ ebuf) {
    __shared__ int h[NBKT], base[NBKT], cur[NBKT];
    for (int i = threadIdx.x; i < NBKT; i += 256) h[i] = 0;
    __syncthreads();
    const int b0 = blockIdx.x * P1_CHUNK;
    for (int i = threadIdx.x; i < P1_CHUNK; i += 256) {
        int e = b0 + i;
        if (e < N_EDGES) atomicAdd(&h[dst[e] >> 9], 1);
    }
    __syncthreads();
    for (int i = threadIdx.x; i < NBKT; i += 256) {
        cur[i] = 0;
        base[i] = h[i] ? atomicAdd(&bkt_cursor[i], h[i]) : 0;
    }
    __syncthreads();
    for (int i = threadIdx.x; i < P1_CHUNK; i += 256) {
        int e = b0 + i;
        if (e < N_EDGES) {
            int d = dst[e];
            int bk = d >> 9;
            int pos = base[bk] + atomicAdd(&cur[bk], 1);
            ebuf[pos] = make_int2(src[e], d);
        }
    }
}

__global__ __launch_bounds__(256) void csr_scatter_kernel(
    const int2* __restrict__ ebuf, const int* __restrict__ bkt_start,
    const int* __restrict__ row_ptr, int* __restrict__ edge_src) {
    __shared__ int cur[512];
    const int bk = blockIdx.x;
    const int n0 = bk << 9;
    for (int i = threadIdx.x; i < 512; i += 256) {
        int n = n0 + i;
        cur[i] = (n < N_NODES) ? row_ptr[n] : 0;
    }
    __syncthreads();
    const int s = bkt_start[bk], e = bkt_start[bk + 1];
    for (int i = s + threadIdx.x; i < e; i += 256) {
        int2 ed = ebuf[i];
        int pos = atomicAdd(&cur[ed.y - n0], 1);
        edge_src[pos] = ed.x;
    }
}

// ---------------- weight convert: Wt[m][n][k] = bf16(W[m][k][n]) ----------------
__global__ __launch_bounds__(256) void convert_wt_kernel(
    const float* __restrict__ Wp, const float* __restrict__ Ws,
    const float* __restrict__ Wn, unsigned short* __restrict__ wt) {
    __shared__ float tile[64][65];
    const int m = blockIdx.x >> 2;
    const int tij = blockIdx.x & 3;
    const int ti = tij >> 1, tj = tij & 1;
    const float* W = (m < 4) ? Wp + (size_t)m * 16384
                   : (m < 8) ? Ws + (size_t)(m - 4) * 16384
                             : Wn + (size_t)(m - 8) * 16384;
#pragma unroll
    for (int i = 0; i < 16; ++i) {
        int e = i * 256 + threadIdx.x;
        int r = e >> 6, c = e & 63;
        tile[r][c] = W[(size_t)(ti * 64 + r) * 128 + tj * 64 + c];
    }
    __syncthreads();
#pragma unroll
    for (int i = 0; i < 16; ++i) {
        int e = i * 256 + threadIdx.x;
        int r = e >> 6, c = e & 63;
        wt[(size_t)m * 16384 + (size_t)(tj * 64 + r) * 128 + ti * 64 + c] = f2b(tile[c][r]);
    }
}

// ---------------- MFMA GEMM: 2 node-groups/wave, W amortized (R12-proven) -----
template <int MODE, bool AF32>
__global__ __launch_bounds__(256, 2) void gemm_kernel(
    const void* __restrict__ xv, const unsigned short* __restrict__ p,
    const unsigned short* __restrict__ W1t, const unsigned short* __restrict__ W2t,
    const float* __restrict__ bias,
    const unsigned short* __restrict__ Wnt, const float* __restrict__ bias_n,
    float* __restrict__ yf, unsigned short* __restrict__ yx,
    unsigned short* __restrict__ yh) {
    __shared__ unsigned short xs[128 * FEAT];  // x' exchange only (MODE 1)
    const int tid = threadIdx.x;
    const int wv = tid >> 6;
    const int lane = tid & 63;
    const int l15 = lane & 15;
    const int lhi = lane >> 4;
    const int n0 = blockIdx.x * 128;
    const int fsub = 4 * lhi;

    int nrow[2], nglob[2], nclamp[2];
#pragma unroll
    for (int g = 0; g < 2; ++g) {
        nrow[g] = (2 * wv + g) * 16 + l15;
        nglob[g] = n0 + nrow[g];
        nclamp[g] = (nglob[g] < N_NODES) ? nglob[g] : (N_NODES - 1);
    }

    bf16x8 xf[2][4];
    if (AF32) {
        const float* x = (const float*)xv;
#pragma unroll
        for (int g = 0; g < 2; ++g)
#pragma unroll
            for (int kk = 0; kk < 4; ++kk) {
                const float4* gp = (const float4*)(x + (size_t)nclamp[g] * FEAT + kk * 32 + lhi * 8);
                float4 v0 = gp[0], v1 = gp[1];
                unsigned short hh[8];
                hh[0] = f2b(v0.x); hh[1] = f2b(v0.y); hh[2] = f2b(v0.z); hh[3] = f2b(v0.w);
                hh[4] = f2b(v1.x); hh[5] = f2b(v1.y); hh[6] = f2b(v1.z); hh[7] = f2b(v1.w);
                xf[g][kk] = *(bf16x8*)hh;
            }
    } else {
        const unsigned short* xb = (const unsigned short*)xv;
#pragma unroll
        for (int g = 0; g < 2; ++g)
#pragma unroll
            for (int kk = 0; kk < 4; ++kk)
                xf[g][kk] = *(const bf16x8*)(xb + (size_t)nclamp[g] * FEAT + kk * 32 + lhi * 8);
    }
    bf16x8 pf[2][4];
    if (MODE >= 1) {
#pragma unroll
        for (int g = 0; g < 2; ++g)
#pragma unroll
            for (int kk = 0; kk < 4; ++kk) {
                int f0 = kk * 32 + lhi * 8;
                int sl = f0 >> 4;
                int off = f0 & 15;
                pf[g][kk] = *(const bf16x8*)(p + ((size_t)sl * N_NODES + nclamp[g]) * 16 + off);
            }
    }

    f32x4 acc[2][8];
#pragma unroll
    for (int g = 0; g < 2; ++g)
#pragma unroll
        for (int q = 0; q < 8; ++q) acc[g][q] = (f32x4)(0.f);

#pragma unroll
    for (int ft = 0; ft < 8; ++ft) {
        const unsigned short* wrow = W1t + (size_t)(ft * 16 + l15) * FEAT;
#pragma unroll
        for (int kk = 0; kk < 4; ++kk) {
            bf16x8 wfrag = *(const bf16x8*)(wrow + kk * 32 + lhi * 8);
            acc[0][ft] = __builtin_amdgcn_mfma_f32_16x16x32_bf16(wfrag, xf[0][kk], acc[0][ft], 0, 0, 0);
            acc[1][ft] = __builtin_amdgcn_mfma_f32_16x16x32_bf16(wfrag, xf[1][kk], acc[1][ft], 0, 0, 0);
        }
    }
    if (MODE >= 1) {
#pragma unroll
        for (int ft = 0; ft < 8; ++ft) {
            const unsigned short* wrow = W2t + (size_t)(ft * 16 + l15) * FEAT;
#pragma unroll
            for (int kk = 0; kk < 4; ++kk) {
                bf16x8 wfrag = *(const bf16x8*)(wrow + kk * 32 + lhi * 8);
                acc[0][ft] = __builtin_amdgcn_mfma_f32_16x16x32_bf16(wfrag, pf[0][kk], acc[0][ft], 0, 0, 0);
                acc[1][ft] = __builtin_amdgcn_mfma_f32_16x16x32_bf16(wfrag, pf[1][kk], acc[1][ft], 0, 0, 0);
            }
        }
    }

#pragma unroll
    for (int g = 0; g < 2; ++g) {
#pragma unroll
        for (int ft = 0; ft < 8; ++ft) {
            float4 bv = ((const float4*)bias)[ft * 4 + lhi];
            float v0 = fmaxf(acc[g][ft][0] + bv.x, 0.f);
            float v1 = fmaxf(acc[g][ft][1] + bv.y, 0.f);
            float v2 = fmaxf(acc[g][ft][2] + bv.z, 0.f);
            float v3 = fmaxf(acc[g][ft][3] + bv.w, 0.f);
            uint2 pk = make_uint2((unsigned)f2b(v0) | ((unsigned)f2b(v1) << 16),
                                  (unsigned)f2b(v2) | ((unsigned)f2b(v3) << 16));
            if (MODE == 0) {
                if (nglob[g] < N_NODES)
                    *(uint2*)(yh + ((size_t)ft * N_NODES + nglob[g]) * 16 + fsub) = pk;
            } else if (MODE == 2) {
                if (nglob[g] < N_NODES)
                    *(float4*)(yf + (size_t)nglob[g] * FEAT + ft * 16 + fsub) =
                        make_float4(v0, v1, v2, v3);
            } else {
                if (nglob[g] < N_NODES)
                    *(uint2*)(yx + (size_t)nglob[g] * FEAT + ft * 16 + fsub) = pk;
                int byte = (nrow[g] * 256 + (ft * 16 + fsub) * 2) ^ ((nrow[g] & 7) << 4);
                *(uint2*)((char*)xs + byte) = pk;   // own band only
            }
        }
    }

    if (MODE == 1) {
        bf16x8 xf2[2][4];
#pragma unroll
        for (int g = 0; g < 2; ++g)
#pragma unroll
            for (int kk = 0; kk < 4; ++kk) {
                int byte = (nrow[g] * 256 + (kk * 32 + lhi * 8) * 2) ^ ((nrow[g] & 7) << 4);
                xf2[g][kk] = *(const bf16x8*)((const char*)xs + byte);
            }
#pragma unroll
        for (int g = 0; g < 2; ++g)
#pragma unroll
            for (int q = 0; q < 8; ++q) acc[g][q] = (f32x4)(0.f);
#pragma unroll
        for (int ft = 0; ft < 8; ++ft) {
            const unsigned short* wrow = Wnt + (size_t)(ft * 16 + l15) * FEAT;
#pragma unroll
            for (int kk = 0; kk < 4; ++kk) {
                bf16x8 wfrag = *(const bf16x8*)(wrow + kk * 32 + lhi * 8);
                acc[0][ft] = __builtin_amdgcn_mfma_f32_16x16x32_bf16(wfrag, xf2[0][kk], acc[0][ft], 0, 0, 0);
                acc[1][ft] = __builtin_amdgcn_mfma_f32_16x16x32_bf16(wfrag, xf2[1][kk], acc[1][ft], 0, 0, 0);
            }
        }
#pragma unroll
        for (int g = 0; g < 2; ++g) {
#pragma unroll
            for (int ft = 0; ft < 8; ++ft) {
                float4 bv = ((const float4*)bias_n)[ft * 4 + lhi];
                float v0 = fmaxf(acc[g][ft][0] + bv.x, 0.f);
                float v1 = fmaxf(acc[g][ft][1] + bv.y, 0.f);
                float v2 = fmaxf(acc[g][ft][2] + bv.z, 0.f);
                float v3 = fmaxf(acc[g][ft][3] + bv.w, 0.f);
                uint2 pk = make_uint2((unsigned)f2b(v0) | ((unsigned)f2b(v1) << 16),
                                      (unsigned)f2b(v2) | ((unsigned)f2b(v3) << 16));
                if (nglob[g] < N_NODES)
                    *(uint2*)(yh + ((size_t)ft * N_NODES + nglob[g]) * 16 + fsub) = pk;
            }
        }
    }
}

// ---------------- segment max: XCD-pinned slices, 8 slots x 16B loads ----------
// h slice-major: hs[s][node][16 feats] bf16 (3.2 MB/slice -> one XCD L2).
// slice = blockIdx.x & 7 (round-robin XCD pin). Block = 4 waves x 4 nodes.
// Per node: 8 edge-slots x 2 f-lanes; each lane loads uint4 (16B = 8 feats).
// Unroll 2 -> 2x16B in flight per lane; ~1.6x fewer instructions per edge.
__global__ __launch_bounds__(256) void seg_max_kernel(
    const unsigned short* __restrict__ hs, const int* __restrict__ row_ptr,
    const int* __restrict__ edge_src, unsigned short* __restrict__ pooled) {
    const int s = blockIdx.x & 7;
    const int g = blockIdx.x >> 3;            // node group of 16
    const int wv = threadIdx.x >> 6;
    const int lane = threadIdx.x & 63;
    const int qn = lane >> 4;                 // node-in-wave 0..3
    const int slot = (lane >> 1) & 7;         // edge slot 0..7
    const int f = lane & 1;                   // feat half 0..1 (8 feats = 16B)
    int node = g * 16 + wv * 4 + qn;
    const bool valid = node < N_NODES;
    node = valid ? node : N_NODES - 1;
    const unsigned short* hbase = hs + (size_t)s * N_NODES * 16;

    const int start = row_ptr[node];
    const int end = row_ptr[node + 1];
    unsigned int a0 = 0u, a1 = 0u, a2 = 0u, a3 = 0u;   // packed 8x bf16 (>=0)
    int i = start + slot;
    for (; i + 8 < end; i += 16) {
        const uint4 v0 = *(const uint4*)(hbase + (size_t)edge_src[i] * 16 + f * 8);
        const uint4 v1 = *(const uint4*)(hbase + (size_t)edge_src[i + 8] * 16 + f * 8);
        a0 = pkmax(a0, v0.x); a1 = pkmax(a1, v0.y);
        a2 = pkmax(a2, v0.z); a3 = pkmax(a3, v0.w);
        a0 = pkmax(a0, v1.x); a1 = pkmax(a1, v1.y);
        a2 = pkmax(a2, v1.z); a3 = pkmax(a3, v1.w);
    }
    if (i < end) {
        const uint4 v0 = *(const uint4*)(hbase + (size_t)edge_src[i] * 16 + f * 8);
        a0 = pkmax(a0, v0.x); a1 = pkmax(a1, v0.y);
        a2 = pkmax(a2, v0.z); a3 = pkmax(a3, v0.w);
    }
    // reduce across the 8 slots (lane bits 1..3)
#pragma unroll
    for (int off = 2; off <= 8; off <<= 1) {
        a0 = pkmax(a0, __shfl_xor(a0, off, 64));
        a1 = pkmax(a1, __shfl_xor(a1, off, 64));
        a2 = pkmax(a2, __shfl_xor(a2, off, 64));
        a3 = pkmax(a3, __shfl_xor(a3, off, 64));
    }
    if (slot == 0 && valid) {
        *(uint4*)(pooled + ((size_t)s * N_NODES + node) * 16 + f * 8) =
            make_uint4(a0, a1, a2, a3);
    }
}

// ---------------- launch ----------------
// ws (~148 MB < proven 161): edge_src 6.4 | ebuf 12.8 | deg 0.4 | bkt_cnt 1K |
// row_ptr 0.4 | blk_sums 2K | bkt_start 1K | bkt_cursor 1K | wt 0.39 |
// bufH 25.6 (slice-major) | bufP 25.6 (slice-major) | bufX0 25.6 | bufX1 25.6
// x chain: feats(f32) -> X0 -> X1 -> X0 -> d_out(f32)

extern "C" void kernel_launch(void* const* d_in, const int* in_sizes, int n_in,
                              void* d_out, int out_size, void* d_ws, size_t ws_size,
                              hipStream_t stream) {
    const float* feats = (const float*)d_in[0];
    const float* Wp = (const float*)d_in[1];
    const float* bp = (const float*)d_in[2];
    const float* Ws = (const float*)d_in[3];
    const float* Wn = (const float*)d_in[4];
    const float* bb = (const float*)d_in[5];
    const int* src = (const int*)d_in[6];
    const int* dst = (const int*)d_in[7];
    float* out = (float*)d_out;

    const size_t NF = (size_t)N_NODES * FEAT;
    char* ws = (char*)d_ws;
    int* edge_src = (int*)ws;    ws += (size_t)N_EDGES * sizeof(int);
    int2* ebuf = (int2*)ws;      ws += (size_t)N_EDGES * sizeof(int2);
    int* deg = (int*)ws;         ws += (size_t)N_NODES * sizeof(int);
    int* bkt_cnt = (int*)ws;     ws += 256 * sizeof(int);
    int* row_ptr = (int*)ws;     ws += (size_t)(N_NODES + 4) * sizeof(int);
    int* blk_sums = (int*)ws;    ws += 512 * sizeof(int);
    int* bkt_start = (int*)ws;   ws += 256 * sizeof(int);
    int* bkt_cursor = (int*)ws;  ws += 256 * sizeof(int);
    unsigned short* wt = (unsigned short*)ws;    ws += (size_t)12 * 16384 * sizeof(unsigned short);
    unsigned short* bufH = (unsigned short*)ws;  ws += NF * sizeof(unsigned short);
    unsigned short* bufP = (unsigned short*)ws;  ws += NF * sizeof(unsigned short);
    unsigned short* bufX0 = (unsigned short*)ws; ws += NF * sizeof(unsigned short);
    unsigned short* bufX1 = (unsigned short*)ws;

    // CSR build (deg & bkt_cnt adjacent -> single memset)
    hipMemsetAsync(deg, 0, ((size_t)N_NODES + 256) * sizeof(int), stream);
    count_deg_kernel<<<N_P1_BLKS, 256, 0, stream>>>(dst, deg, bkt_cnt);
    blk_sum_kernel<<<N_SCAN_BLKS, SCAN_BLK, 0, stream>>>(deg, blk_sums);
    scan_all_kernel<<<1, 512, 0, stream>>>(blk_sums, bkt_cnt, bkt_start, bkt_cursor);
    write_rowptr_kernel<<<N_SCAN_BLKS, SCAN_BLK, 0, stream>>>(deg, blk_sums, row_ptr);
    bucket_scatter_kernel<<<N_P1_BLKS, 256, 0, stream>>>(src, dst, bkt_cursor, ebuf);
    csr_scatter_kernel<<<NBKT, 256, 0, stream>>>(ebuf, bkt_start, row_ptr, edge_src);
    convert_wt_kernel<<<48, 256, 0, stream>>>(Wp, Ws, Wn, wt);

    const int seg_grid = ((N_NODES + 15) / 16) * 8;   // 6250 groups x 8 slices

    const unsigned short* xb[LAYERS] = {nullptr, bufX0, bufX1, bufX0};
    unsigned short* xo[LAYERS] = {bufX0, bufX1, bufX0, nullptr};

    // layer 0 h_pool
    gemm_kernel<0, true><<<GEMM_GRID, 256, 0, stream>>>(
        feats, nullptr, wt, nullptr, bp, nullptr, nullptr, nullptr, nullptr, bufH);

    for (int l = 0; l < LAYERS; ++l) {
        const unsigned short* WsT = wt + (size_t)(4 + l) * 16384;
        const unsigned short* WnT = wt + (size_t)(8 + l) * 16384;
        const float* bl = bb + (size_t)l * FEAT;

        seg_max_kernel<<<seg_grid, 256, 0, stream>>>(bufH, row_ptr, edge_src, bufP);

        if (l == 0) {
            gemm_kernel<1, true><<<GEMM_GRID, 256, 0, stream>>>(
                feats, bufP, WsT, WnT, bl, wt + (size_t)(l + 1) * 16384,
                bp + (size_t)(l + 1) * FEAT, nullptr, xo[l], bufH);
        } else if (l < LAYERS - 1) {
            gemm_kernel<1, false><<<GEMM_GRID, 256, 0, stream>>>(
                xb[l], bufP, WsT, WnT, bl, wt + (size_t)(l + 1) * 16384,
                bp + (size_t)(l + 1) * FEAT, nullptr, xo[l], bufH);
        } else {
            gemm_kernel<2, false><<<GEMM_GRID, 256, 0, stream>>>(
                xb[l], bufP, WsT, WnT, bl, nullptr, nullptr, out, nullptr, nullptr);
        }
    }
}

// Round 14
// 701.756 us; speedup vs baseline: 1.3909x; 1.0185x over previous
//
#include <hip/hip_runtime.h>

#define N_NODES 100000
#define NP (N_NODES + 8)                                   // padded (8 zero rows/slice)
#define N_EDGES 1600000
#define FEAT 128
#define LAYERS 4
#define SCAN_BLK 256
#define N_SCAN_BLKS ((N_NODES + SCAN_BLK - 1) / SCAN_BLK)  // 391
#define NBKT ((N_NODES + 511) >> 9)                        // 196 buckets x 512 nodes
#define P1_CHUNK 4096
#define N_P1_BLKS ((N_EDGES + P1_CHUNK - 1) / P1_CHUNK)    // 391
#define GEMM_GRID ((N_NODES + 127) / 128)                  // 782 (128 nodes/block)

typedef __attribute__((ext_vector_type(8))) short bf16x8;
typedef __attribute__((ext_vector_type(4))) float f32x4;

__device__ __forceinline__ unsigned short f2b(float f) {   // f32 -> bf16 RNE
    union { float f; unsigned int u; } v; v.f = f;
    unsigned int u = v.u;
    return (unsigned short)((u + 0x7fffu + ((u >> 16) & 1u)) >> 16);
}

// packed max of 2x bf16 (valid for non-negative bf16: bit pattern is monotone)
__device__ __forceinline__ unsigned int pkmax(unsigned int a, unsigned int b) {
    unsigned int r;
    asm("v_pk_max_u16 %0, %1, %2" : "=v"(r) : "v"(a), "v"(b));
    return r;
}

// ---------------- CSR build (bucketed) ----------------

__global__ __launch_bounds__(256) void count_deg_kernel(const int* __restrict__ dst,
                                                        int* __restrict__ deg,
                                                        int* __restrict__ bkt_cnt) {
    __shared__ int h[NBKT];
    for (int i = threadIdx.x; i < NBKT; i += 256) h[i] = 0;
    __syncthreads();
    const int base = blockIdx.x * P1_CHUNK;
    for (int i = threadIdx.x; i < P1_CHUNK; i += 256) {
        int e = base + i;
        if (e < N_EDGES) {
            int d = dst[e];
            atomicAdd(&deg[d], 1);
            atomicAdd(&h[d >> 9], 1);
        }
    }
    __syncthreads();
    for (int i = threadIdx.x; i < NBKT; i += 256)
        if (h[i]) atomicAdd(&bkt_cnt[i], h[i]);
}

__global__ __launch_bounds__(SCAN_BLK) void blk_sum_kernel(const int* __restrict__ deg,
                                                           int* __restrict__ blk_sums) {
    int i = blockIdx.x * SCAN_BLK + threadIdx.x;
    int v = (i < N_NODES) ? deg[i] : 0;
#pragma unroll
    for (int off = 32; off; off >>= 1) v += __shfl_down(v, off, 64);
    __shared__ int ws_[SCAN_BLK / 64];
    if ((threadIdx.x & 63) == 0) ws_[threadIdx.x >> 6] = v;
    __syncthreads();
    if (threadIdx.x == 0) {
        int s = 0;
#pragma unroll
        for (int w = 0; w < SCAN_BLK / 64; ++w) s += ws_[w];
        blk_sums[blockIdx.x] = s;
    }
}

__global__ __launch_bounds__(512) void scan_all_kernel(int* __restrict__ blk_sums,
                                                       const int* __restrict__ bkt_cnt,
                                                       int* __restrict__ bkt_start,
                                                       int* __restrict__ bkt_cursor) {
    __shared__ int s[512];
    __shared__ int b[256];
    const int t = threadIdx.x;
    s[t] = (t < N_SCAN_BLKS) ? blk_sums[t] : 0;
    if (t < 256) b[t] = (t < NBKT) ? bkt_cnt[t] : 0;
    __syncthreads();
    for (int off = 1; off < 512; off <<= 1) {
        int v = (t >= off) ? s[t - off] : 0;
        __syncthreads();
        s[t] += v;
        __syncthreads();
    }
    for (int off = 1; off < 256; off <<= 1) {
        int v = (t < 256 && t >= off) ? b[t - off] : 0;
        __syncthreads();
        if (t < 256) b[t] += v;
        __syncthreads();
    }
    if (t < N_SCAN_BLKS) blk_sums[t] = (t == 0) ? 0 : s[t - 1];
    if (t < NBKT) {
        int st = (t == 0) ? 0 : b[t - 1];
        bkt_start[t] = st;
        bkt_cursor[t] = st;
    }
    if (t == 0) bkt_start[NBKT] = N_EDGES;
}

__global__ __launch_bounds__(SCAN_BLK) void write_rowptr_kernel(
    const int* __restrict__ deg, const int* __restrict__ blk_off,
    int* __restrict__ row_ptr) {
    __shared__ int s[SCAN_BLK];
    const int t = threadIdx.x;
    const int i = blockIdx.x * SCAN_BLK + t;
    int v = (i < N_NODES) ? deg[i] : 0;
    s[t] = v;
    __syncthreads();
    for (int off = 1; off < SCAN_BLK; off <<= 1) {
        int u = (t >= off) ? s[t - off] : 0;
        __syncthreads();
        s[t] += u;
        __syncthreads();
    }
    int excl = s[t] - v + blk_off[blockIdx.x];
    if (i < N_NODES) row_ptr[i] = excl;
    if (i == 0) row_ptr[N_NODES] = N_EDGES;
}

__global__ __launch_bounds__(256) void bucket_scatter_kernel(
    const int* __restrict__ src, const int* __restrict__ dst,
    int* __restrict__ bkt_cursor, int2* __restrict__ ebuf) {
    __shared__ int h[NBKT], base[NBKT], cur[NBKT];
    for (int i = threadIdx.x; i < NBKT; i += 256) h[i] = 0;
    __syncthreads();
    const int b0 = blockIdx.x * P1_CHUNK;
    for (int i = threadIdx.x; i < P1_CHUNK; i += 256) {
        int e = b0 + i;
        if (e < N_EDGES) atomicAdd(&h[dst[e] >> 9], 1);
    }
    __syncthreads();
    for (int i = threadIdx.x; i < NBKT; i += 256) {
        cur[i] = 0;
        base[i] = h[i] ? atomicAdd(&bkt_cursor[i], h[i]) : 0;
    }
    __syncthreads();
    for (int i = threadIdx.x; i < P1_CHUNK; i += 256) {
        int e = b0 + i;
        if (e < N_EDGES) {
            int d = dst[e];
            int bk = d >> 9;
            int pos = base[bk] + atomicAdd(&cur[bk], 1);
            ebuf[pos] = make_int2(src[e], d);
        }
    }
}

__global__ __launch_bounds__(256) void csr_scatter_kernel(
    const int2* __restrict__ ebuf, const int* __restrict__ bkt_start,
    const int* __restrict__ row_ptr, int* __restrict__ edge_src) {
    __shared__ int cur[512];
    const int bk = blockIdx.x;
    const int n0 = bk << 9;
    for (int i = threadIdx.x; i < 512; i += 256) {
        int n = n0 + i;
        cur[i] = (n < N_NODES) ? row_ptr[n] : 0;
    }
    __syncthreads();
    const int s = bkt_start[bk], e = bkt_start[bk + 1];
    for (int i = s + threadIdx.x; i < e; i += 256) {
        int2 ed = ebuf[i];
        int pos = atomicAdd(&cur[ed.y - n0], 1);
        edge_src[pos] = ed.x;
    }
}

// ------- weight convert + bufH pad-row zeroing (block 48) -------
__global__ __launch_bounds__(256) void convert_wt_kernel(
    const float* __restrict__ Wp, const float* __restrict__ Ws,
    const float* __restrict__ Wn, unsigned short* __restrict__ wt,
    unsigned short* __restrict__ hpad) {
    if (blockIdx.x == 48) {
        // zero the 8 pad rows of each of the 8 slices of bufH
        for (int idx = threadIdx.x; idx < 8 * 8 * 16; idx += 256) {
            int s = idx >> 7;            // slice
            int rc = idx & 127;          // row*16+c
            hpad[((size_t)s * NP + N_NODES) * 16 + rc] = 0;
        }
        return;
    }
    __shared__ float tile[64][65];
    const int m = blockIdx.x >> 2;
    const int tij = blockIdx.x & 3;
    const int ti = tij >> 1, tj = tij & 1;
    const float* W = (m < 4) ? Wp + (size_t)m * 16384
                   : (m < 8) ? Ws + (size_t)(m - 4) * 16384
                             : Wn + (size_t)(m - 8) * 16384;
#pragma unroll
    for (int i = 0; i < 16; ++i) {
        int e = i * 256 + threadIdx.x;
        int r = e >> 6, c = e & 63;
        tile[r][c] = W[(size_t)(ti * 64 + r) * 128 + tj * 64 + c];
    }
    __syncthreads();
#pragma unroll
    for (int i = 0; i < 16; ++i) {
        int e = i * 256 + threadIdx.x;
        int r = e >> 6, c = e & 63;
        wt[(size_t)m * 16384 + (size_t)(tj * 64 + r) * 128 + ti * 64 + c] = f2b(tile[c][r]);
    }
}

// ---------------- MFMA GEMM: 2 node-groups/wave, W amortized (R12-proven) -----
// yh (slice-major h output) uses PADDED stride NP; p (pooled) uses stride N_NODES.
template <int MODE, bool AF32>
__global__ __launch_bounds__(256, 2) void gemm_kernel(
    const void* __restrict__ xv, const unsigned short* __restrict__ p,
    const unsigned short* __restrict__ W1t, const unsigned short* __restrict__ W2t,
    const float* __restrict__ bias,
    const unsigned short* __restrict__ Wnt, const float* __restrict__ bias_n,
    float* __restrict__ yf, unsigned short* __restrict__ yx,
    unsigned short* __restrict__ yh) {
    __shared__ unsigned short xs[128 * FEAT];  // x' exchange only (MODE 1)
    const int tid = threadIdx.x;
    const int wv = tid >> 6;
    const int lane = tid & 63;
    const int l15 = lane & 15;
    const int lhi = lane >> 4;
    const int n0 = blockIdx.x * 128;
    const int fsub = 4 * lhi;

    int nrow[2], nglob[2], nclamp[2];
#pragma unroll
    for (int g = 0; g < 2; ++g) {
        nrow[g] = (2 * wv + g) * 16 + l15;
        nglob[g] = n0 + nrow[g];
        nclamp[g] = (nglob[g] < N_NODES) ? nglob[g] : (N_NODES - 1);
    }

    bf16x8 xf[2][4];
    if (AF32) {
        const float* x = (const float*)xv;
#pragma unroll
        for (int g = 0; g < 2; ++g)
#pragma unroll
            for (int kk = 0; kk < 4; ++kk) {
                const float4* gp = (const float4*)(x + (size_t)nclamp[g] * FEAT + kk * 32 + lhi * 8);
                float4 v0 = gp[0], v1 = gp[1];
                unsigned short hh[8];
                hh[0] = f2b(v0.x); hh[1] = f2b(v0.y); hh[2] = f2b(v0.z); hh[3] = f2b(v0.w);
                hh[4] = f2b(v1.x); hh[5] = f2b(v1.y); hh[6] = f2b(v1.z); hh[7] = f2b(v1.w);
                xf[g][kk] = *(bf16x8*)hh;
            }
    } else {
        const unsigned short* xb = (const unsigned short*)xv;
#pragma unroll
        for (int g = 0; g < 2; ++g)
#pragma unroll
            for (int kk = 0; kk < 4; ++kk)
                xf[g][kk] = *(const bf16x8*)(xb + (size_t)nclamp[g] * FEAT + kk * 32 + lhi * 8);
    }
    bf16x8 pf[2][4];
    if (MODE >= 1) {
#pragma unroll
        for (int g = 0; g < 2; ++g)
#pragma unroll
            for (int kk = 0; kk < 4; ++kk) {
                int f0 = kk * 32 + lhi * 8;
                int sl = f0 >> 4;
                int off = f0 & 15;
                pf[g][kk] = *(const bf16x8*)(p + ((size_t)sl * N_NODES + nclamp[g]) * 16 + off);
            }
    }

    f32x4 acc[2][8];
#pragma unroll
    for (int g = 0; g < 2; ++g)
#pragma unroll
        for (int q = 0; q < 8; ++q) acc[g][q] = (f32x4)(0.f);

#pragma unroll
    for (int ft = 0; ft < 8; ++ft) {
        const unsigned short* wrow = W1t + (size_t)(ft * 16 + l15) * FEAT;
#pragma unroll
        for (int kk = 0; kk < 4; ++kk) {
            bf16x8 wfrag = *(const bf16x8*)(wrow + kk * 32 + lhi * 8);
            acc[0][ft] = __builtin_amdgcn_mfma_f32_16x16x32_bf16(wfrag, xf[0][kk], acc[0][ft], 0, 0, 0);
            acc[1][ft] = __builtin_amdgcn_mfma_f32_16x16x32_bf16(wfrag, xf[1][kk], acc[1][ft], 0, 0, 0);
        }
    }
    if (MODE >= 1) {
#pragma unroll
        for (int ft = 0; ft < 8; ++ft) {
            const unsigned short* wrow = W2t + (size_t)(ft * 16 + l15) * FEAT;
#pragma unroll
            for (int kk = 0; kk < 4; ++kk) {
                bf16x8 wfrag = *(const bf16x8*)(wrow + kk * 32 + lhi * 8);
                acc[0][ft] = __builtin_amdgcn_mfma_f32_16x16x32_bf16(wfrag, pf[0][kk], acc[0][ft], 0, 0, 0);
                acc[1][ft] = __builtin_amdgcn_mfma_f32_16x16x32_bf16(wfrag, pf[1][kk], acc[1][ft], 0, 0, 0);
            }
        }
    }

#pragma unroll
    for (int g = 0; g < 2; ++g) {
#pragma unroll
        for (int ft = 0; ft < 8; ++ft) {
            float4 bv = ((const float4*)bias)[ft * 4 + lhi];
            float v0 = fmaxf(acc[g][ft][0] + bv.x, 0.f);
            float v1 = fmaxf(acc[g][ft][1] + bv.y, 0.f);
            float v2 = fmaxf(acc[g][ft][2] + bv.z, 0.f);
            float v3 = fmaxf(acc[g][ft][3] + bv.w, 0.f);
            uint2 pk = make_uint2((unsigned)f2b(v0) | ((unsigned)f2b(v1) << 16),
                                  (unsigned)f2b(v2) | ((unsigned)f2b(v3) << 16));
            if (MODE == 0) {
                if (nglob[g] < N_NODES)
                    *(uint2*)(yh + ((size_t)ft * NP + nglob[g]) * 16 + fsub) = pk;
            } else if (MODE == 2) {
                if (nglob[g] < N_NODES)
                    *(float4*)(yf + (size_t)nglob[g] * FEAT + ft * 16 + fsub) =
                        make_float4(v0, v1, v2, v3);
            } else {
                if (nglob[g] < N_NODES)
                    *(uint2*)(yx + (size_t)nglob[g] * FEAT + ft * 16 + fsub) = pk;
                int byte = (nrow[g] * 256 + (ft * 16 + fsub) * 2) ^ ((nrow[g] & 7) << 4);
                *(uint2*)((char*)xs + byte) = pk;   // own band only
            }
        }
    }

    if (MODE == 1) {
        bf16x8 xf2[2][4];
#pragma unroll
        for (int g = 0; g < 2; ++g)
#pragma unroll
            for (int kk = 0; kk < 4; ++kk) {
                int byte = (nrow[g] * 256 + (kk * 32 + lhi * 8) * 2) ^ ((nrow[g] & 7) << 4);
                xf2[g][kk] = *(const bf16x8*)((const char*)xs + byte);
            }
#pragma unroll
        for (int g = 0; g < 2; ++g)
#pragma unroll
            for (int q = 0; q < 8; ++q) acc[g][q] = (f32x4)(0.f);
#pragma unroll
        for (int ft = 0; ft < 8; ++ft) {
            const unsigned short* wrow = Wnt + (size_t)(ft * 16 + l15) * FEAT;
#pragma unroll
            for (int kk = 0; kk < 4; ++kk) {
                bf16x8 wfrag = *(const bf16x8*)(wrow + kk * 32 + lhi * 8);
                acc[0][ft] = __builtin_amdgcn_mfma_f32_16x16x32_bf16(wfrag, xf2[0][kk], acc[0][ft], 0, 0, 0);
                acc[1][ft] = __builtin_amdgcn_mfma_f32_16x16x32_bf16(wfrag, xf2[1][kk], acc[1][ft], 0, 0, 0);
            }
        }
#pragma unroll
        for (int g = 0; g < 2; ++g) {
#pragma unroll
            for (int ft = 0; ft < 8; ++ft) {
                float4 bv = ((const float4*)bias_n)[ft * 4 + lhi];
                float v0 = fmaxf(acc[g][ft][0] + bv.x, 0.f);
                float v1 = fmaxf(acc[g][ft][1] + bv.y, 0.f);
                float v2 = fmaxf(acc[g][ft][2] + bv.z, 0.f);
                float v3 = fmaxf(acc[g][ft][3] + bv.w, 0.f);
                uint2 pk = make_uint2((unsigned)f2b(v0) | ((unsigned)f2b(v1) << 16),
                                      (unsigned)f2b(v2) | ((unsigned)f2b(v3) << 16));
                if (nglob[g] < N_NODES)
                    *(uint2*)(yh + ((size_t)ft * NP + nglob[g]) * 16 + fsub) = pk;
            }
        }
    }
}

// ------- segment max: XCD-pinned slices, index-prefetch, branch-free body -------
// h slice-major PADDED: hs[s][NP][16]; rows N_NODES.. are zeros (pkmax identity).
// Out-of-range slots clamp their edge index to the zero row -> no branch in body.
// Index loads for trip t+1 issue BEFORE trip t's gathers -> L3 index latency
// hides under L2 gather latency.
__global__ __launch_bounds__(256) void seg_max_kernel(
    const unsigned short* __restrict__ hs, const int* __restrict__ row_ptr,
    const int* __restrict__ edge_src, unsigned short* __restrict__ pooled) {
    const int s = blockIdx.x & 7;
    const int g = blockIdx.x >> 3;            // node group of 16
    const int wv = threadIdx.x >> 6;
    const int lane = threadIdx.x & 63;
    const int qn = lane >> 4;                 // node-in-wave 0..3
    const int slot = (lane >> 1) & 7;         // edge slot 0..7
    const int f = lane & 1;                   // feat half 0..1 (8 feats = 16B)
    int node = g * 16 + wv * 4 + qn;
    const bool valid = node < N_NODES;
    node = valid ? node : N_NODES - 1;
    const unsigned short* hbase = hs + (size_t)s * NP * 16;

    const int start = row_ptr[node];
    const int end = row_ptr[node + 1];
    unsigned int a0 = 0u, a1 = 0u, a2 = 0u, a3 = 0u;   // packed 8x bf16 (>=0)

    int i = start + slot;
    int e0 = (i < end) ? edge_src[i] : N_NODES;        // N_NODES = zero row
    int e1 = (i + 8 < end) ? edge_src[i + 8] : N_NODES;
    for (; i < end; i += 16) {
        int ne0 = (i + 16 < end) ? edge_src[i + 16] : N_NODES;  // prefetch next trip
        int ne1 = (i + 24 < end) ? edge_src[i + 24] : N_NODES;
        const uint4 v0 = *(const uint4*)(hbase + (size_t)e0 * 16 + f * 8);
        const uint4 v1 = *(const uint4*)(hbase + (size_t)e1 * 16 + f * 8);
        a0 = pkmax(a0, v0.x); a1 = pkmax(a1, v0.y);
        a2 = pkmax(a2, v0.z); a3 = pkmax(a3, v0.w);
        a0 = pkmax(a0, v1.x); a1 = pkmax(a1, v1.y);
        a2 = pkmax(a2, v1.z); a3 = pkmax(a3, v1.w);
        e0 = ne0; e1 = ne1;
    }
    // reduce across the 8 slots (lane bits 1..3)
#pragma unroll
    for (int off = 2; off <= 8; off <<= 1) {
        a0 = pkmax(a0, __shfl_xor(a0, off, 64));
        a1 = pkmax(a1, __shfl_xor(a1, off, 64));
        a2 = pkmax(a2, __shfl_xor(a2, off, 64));
        a3 = pkmax(a3, __shfl_xor(a3, off, 64));
    }
    if (slot == 0 && valid) {
        *(uint4*)(pooled + ((size_t)s * N_NODES + node) * 16 + f * 8) =
            make_uint4(a0, a1, a2, a3);
    }
}

// ---------------- launch ----------------
// ws (~148 MB < proven 161): edge_src 6.4 | ebuf 12.8 | deg 0.4 | bkt_cnt 1K |
// row_ptr 0.4 | blk_sums 2K | bkt_start 1K | bkt_cursor 1K | wt 0.39 |
// bufH 25.6+2K (slice-major PADDED) | bufP 25.6 (slice-major) | bufX0/X1 25.6 ea
// x chain: feats(f32) -> X0 -> X1 -> X0 -> d_out(f32)

extern "C" void kernel_launch(void* const* d_in, const int* in_sizes, int n_in,
                              void* d_out, int out_size, void* d_ws, size_t ws_size,
                              hipStream_t stream) {
    const float* feats = (const float*)d_in[0];
    const float* Wp = (const float*)d_in[1];
    const float* bp = (const float*)d_in[2];
    const float* Ws = (const float*)d_in[3];
    const float* Wn = (const float*)d_in[4];
    const float* bb = (const float*)d_in[5];
    const int* src = (const int*)d_in[6];
    const int* dst = (const int*)d_in[7];
    float* out = (float*)d_out;

    const size_t NF = (size_t)N_NODES * FEAT;
    char* ws = (char*)d_ws;
    int* edge_src = (int*)ws;    ws += (size_t)N_EDGES * sizeof(int);
    int2* ebuf = (int2*)ws;      ws += (size_t)N_EDGES * sizeof(int2);
    int* deg = (int*)ws;         ws += (size_t)N_NODES * sizeof(int);
    int* bkt_cnt = (int*)ws;     ws += 256 * sizeof(int);
    int* row_ptr = (int*)ws;     ws += (size_t)(N_NODES + 4) * sizeof(int);
    int* blk_sums = (int*)ws;    ws += 512 * sizeof(int);
    int* bkt_start = (int*)ws;   ws += 256 * sizeof(int);
    int* bkt_cursor = (int*)ws;  ws += 256 * sizeof(int);
    unsigned short* wt = (unsigned short*)ws;    ws += (size_t)12 * 16384 * sizeof(unsigned short);
    unsigned short* bufH = (unsigned short*)ws;  ws += (size_t)8 * NP * 16 * sizeof(unsigned short);
    unsigned short* bufP = (unsigned short*)ws;  ws += NF * sizeof(unsigned short);
    unsigned short* bufX0 = (unsigned short*)ws; ws += NF * sizeof(unsigned short);
    unsigned short* bufX1 = (unsigned short*)ws;

    // CSR build (deg & bkt_cnt adjacent -> single memset)
    hipMemsetAsync(deg, 0, ((size_t)N_NODES + 256) * sizeof(int), stream);
    count_deg_kernel<<<N_P1_BLKS, 256, 0, stream>>>(dst, deg, bkt_cnt);
    blk_sum_kernel<<<N_SCAN_BLKS, SCAN_BLK, 0, stream>>>(deg, blk_sums);
    scan_all_kernel<<<1, 512, 0, stream>>>(blk_sums, bkt_cnt, bkt_start, bkt_cursor);
    write_rowptr_kernel<<<N_SCAN_BLKS, SCAN_BLK, 0, stream>>>(deg, blk_sums, row_ptr);
    bucket_scatter_kernel<<<N_P1_BLKS, 256, 0, stream>>>(src, dst, bkt_cursor, ebuf);
    csr_scatter_kernel<<<NBKT, 256, 0, stream>>>(ebuf, bkt_start, row_ptr, edge_src);
    convert_wt_kernel<<<49, 256, 0, stream>>>(Wp, Ws, Wn, wt, bufH);

    const int seg_grid = ((N_NODES + 15) / 16) * 8;   // 6250 groups x 8 slices

    const unsigned short* xb[LAYERS] = {nullptr, bufX0, bufX1, bufX0};
    unsigned short* xo[LAYERS] = {bufX0, bufX1, bufX0, nullptr};

    // layer 0 h_pool
    gemm_kernel<0, true><<<GEMM_GRID, 256, 0, stream>>>(
        feats, nullptr, wt, nullptr, bp, nullptr, nullptr, nullptr, nullptr, bufH);

    for (int l = 0; l < LAYERS; ++l) {
        const unsigned short* WsT = wt + (size_t)(4 + l) * 16384;
        const unsigned short* WnT = wt + (size_t)(8 + l) * 16384;
        const float* bl = bb + (size_t)l * FEAT;

        seg_max_kernel<<<seg_grid, 256, 0, stream>>>(bufH, row_ptr, edge_src, bufP);

        if (l == 0) {
            gemm_kernel<1, true><<<GEMM_GRID, 256, 0, stream>>>(
                feats, bufP, WsT, WnT, bl, wt + (size_t)(l + 1) * 16384,
                bp + (size_t)(l + 1) * FEAT, nullptr, xo[l], bufH);
        } else if (l < LAYERS - 1) {
            gemm_kernel<1, false><<<GEMM_GRID, 256, 0, stream>>>(
                xb[l], bufP, WsT, WnT, bl, wt + (size_t)(l + 1) * 16384,
                bp + (size_t)(l + 1) * FEAT, nullptr, xo[l], bufH);
        } else {
            gemm_kernel<2, false><<<GEMM_GRID, 256, 0, stream>>>(
                xb[l], bufP, WsT, WnT, bl, nullptr, nullptr, out, nullptr, nullptr);
        }
    }
}

// Round 15
// 581.889 us; speedup vs baseline: 1.6774x; 1.2060x over previous
//
#include <hip/hip_runtime.h>

#define N_NODES 100000
#define NP (N_NODES + 8)                                   // padded (8 zero rows/slice)
#define N_EDGES 1600000
#define FEAT 128
#define LAYERS 4
#define SCAN_BLK 256
#define N_SCAN_BLKS ((N_NODES + SCAN_BLK - 1) / SCAN_BLK)  // 391
#define NBKT ((N_NODES + 511) >> 9)                        // 196 buckets x 512 nodes
#define P1_CHUNK 4096
#define N_P1_BLKS ((N_EDGES + P1_CHUNK - 1) / P1_CHUNK)    // 391
#define GEMM_GRID ((N_NODES + 127) / 128)                  // 782 (128 nodes/block)

typedef __attribute__((ext_vector_type(8))) short bf16x8;
typedef __attribute__((ext_vector_type(4))) float f32x4;

__device__ __forceinline__ unsigned short f2b(float f) {   // f32 -> bf16 RNE
    union { float f; unsigned int u; } v; v.f = f;
    unsigned int u = v.u;
    return (unsigned short)((u + 0x7fffu + ((u >> 16) & 1u)) >> 16);
}

// packed max of 2x bf16 (valid for non-negative bf16: bit pattern is monotone)
__device__ __forceinline__ unsigned int pkmax(unsigned int a, unsigned int b) {
    unsigned int r;
    asm("v_pk_max_u16 %0, %1, %2" : "=v"(r) : "v"(a), "v"(b));
    return r;
}

// ---------------- CSR build (bucketed) ----------------

__global__ __launch_bounds__(256) void count_deg_kernel(const int* __restrict__ dst,
                                                        int* __restrict__ deg,
                                                        int* __restrict__ bkt_cnt) {
    __shared__ int h[NBKT];
    for (int i = threadIdx.x; i < NBKT; i += 256) h[i] = 0;
    __syncthreads();
    const int base = blockIdx.x * P1_CHUNK;
    for (int i = threadIdx.x; i < P1_CHUNK; i += 256) {
        int e = base + i;
        if (e < N_EDGES) {
            int d = dst[e];
            atomicAdd(&deg[d], 1);
            atomicAdd(&h[d >> 9], 1);
        }
    }
    __syncthreads();
    for (int i = threadIdx.x; i < NBKT; i += 256)
        if (h[i]) atomicAdd(&bkt_cnt[i], h[i]);
}

__global__ __launch_bounds__(SCAN_BLK) void blk_sum_kernel(const int* __restrict__ deg,
                                                           int* __restrict__ blk_sums) {
    int i = blockIdx.x * SCAN_BLK + threadIdx.x;
    int v = (i < N_NODES) ? deg[i] : 0;
#pragma unroll
    for (int off = 32; off; off >>= 1) v += __shfl_down(v, off, 64);
    __shared__ int ws_[SCAN_BLK / 64];
    if ((threadIdx.x & 63) == 0) ws_[threadIdx.x >> 6] = v;
    __syncthreads();
    if (threadIdx.x == 0) {
        int s = 0;
#pragma unroll
        for (int w = 0; w < SCAN_BLK / 64; ++w) s += ws_[w];
        blk_sums[blockIdx.x] = s;
    }
}

__global__ __launch_bounds__(512) void scan_all_kernel(int* __restrict__ blk_sums,
                                                       const int* __restrict__ bkt_cnt,
                                                       int* __restrict__ bkt_start,
                                                       int* __restrict__ bkt_cursor) {
    __shared__ int s[512];
    __shared__ int b[256];
    const int t = threadIdx.x;
    s[t] = (t < N_SCAN_BLKS) ? blk_sums[t] : 0;
    if (t < 256) b[t] = (t < NBKT) ? bkt_cnt[t] : 0;
    __syncthreads();
    for (int off = 1; off < 512; off <<= 1) {
        int v = (t >= off) ? s[t - off] : 0;
        __syncthreads();
        s[t] += v;
        __syncthreads();
    }
    for (int off = 1; off < 256; off <<= 1) {
        int v = (t < 256 && t >= off) ? b[t - off] : 0;
        __syncthreads();
        if (t < 256) b[t] += v;
        __syncthreads();
    }
    if (t < N_SCAN_BLKS) blk_sums[t] = (t == 0) ? 0 : s[t - 1];
    if (t < NBKT) {
        int st = (t == 0) ? 0 : b[t - 1];
        bkt_start[t] = st;
        bkt_cursor[t] = st;
    }
    if (t == 0) bkt_start[NBKT] = N_EDGES;
}

__global__ __launch_bounds__(SCAN_BLK) void write_rowptr_kernel(
    const int* __restrict__ deg, const int* __restrict__ blk_off,
    int* __restrict__ row_ptr) {
    __shared__ int s[SCAN_BLK];
    const int t = threadIdx.x;
    const int i = blockIdx.x * SCAN_BLK + t;
    int v = (i < N_NODES) ? deg[i] : 0;
    s[t] = v;
    __syncthreads();
    for (int off = 1; off < SCAN_BLK; off <<= 1) {
        int u = (t >= off) ? s[t - off] : 0;
        __syncthreads();
        s[t] += u;
        __syncthreads();
    }
    int excl = s[t] - v + blk_off[blockIdx.x];
    if (i < N_NODES) row_ptr[i] = excl;
    if (i == 0) row_ptr[N_NODES] = N_EDGES;
}

__global__ __launch_bounds__(256) void bucket_scatter_kernel(
    const int* __restrict__ src, const int* __restrict__ dst,
    int* __restrict__ bkt_cursor, int2* __restrict__ ebuf) {
    __shared__ int h[NBKT], base[NBKT], cur[NBKT];
    for (int i = threadIdx.x; i < NBKT; i += 256) h[i] = 0;
    __syncthreads();
    const int b0 = blockIdx.x * P1_CHUNK;
    for (int i = threadIdx.x; i < P1_CHUNK; i += 256) {
        int e = b0 + i;
        if (e < N_EDGES) atomicAdd(&h[dst[e] >> 9], 1);
    }
    __syncthreads();
    for (int i = threadIdx.x; i < NBKT; i += 256) {
        cur[i] = 0;
        base[i] = h[i] ? atomicAdd(&bkt_cursor[i], h[i]) : 0;
    }
    __syncthreads();
    for (int i = threadIdx.x; i < P1_CHUNK; i += 256) {
        int e = b0 + i;
        if (e < N_EDGES) {
            int d = dst[e];
            int bk = d >> 9;
            int pos = base[bk] + atomicAdd(&cur[bk], 1);
            ebuf[pos] = make_int2(src[e], d);
        }
    }
}

__global__ __launch_bounds__(256) void csr_scatter_kernel(
    const int2* __restrict__ ebuf, const int* __restrict__ bkt_start,
    const int* __restrict__ row_ptr, int* __restrict__ edge_src) {
    __shared__ int cur[512];
    const int bk = blockIdx.x;
    const int n0 = bk << 9;
    for (int i = threadIdx.x; i < 512; i += 256) {
        int n = n0 + i;
        cur[i] = (n < N_NODES) ? row_ptr[n] : 0;
    }
    __syncthreads();
    const int s = bkt_start[bk], e = bkt_start[bk + 1];
    for (int i = s + threadIdx.x; i < e; i += 256) {
        int2 ed = ebuf[i];
        int pos = atomicAdd(&cur[ed.y - n0], 1);
        edge_src[pos] = ed.x;
    }
}

// ------- weight convert + bufH pad-row zeroing (block 48) -------
__global__ __launch_bounds__(256) void convert_wt_kernel(
    const float* __restrict__ Wp, const float* __restrict__ Ws,
    const float* __restrict__ Wn, unsigned short* __restrict__ wt,
    unsigned short* __restrict__ hpad) {
    if (blockIdx.x == 48) {
        for (int idx = threadIdx.x; idx < 8 * 8 * 16; idx += 256) {
            int s = idx >> 7;
            int rc = idx & 127;
            hpad[((size_t)s * NP + N_NODES) * 16 + rc] = 0;
        }
        return;
    }
    __shared__ float tile[64][65];
    const int m = blockIdx.x >> 2;
    const int tij = blockIdx.x & 3;
    const int ti = tij >> 1, tj = tij & 1;
    const float* W = (m < 4) ? Wp + (size_t)m * 16384
                   : (m < 8) ? Ws + (size_t)(m - 4) * 16384
                             : Wn + (size_t)(m - 8) * 16384;
#pragma unroll
    for (int i = 0; i < 16; ++i) {
        int e = i * 256 + threadIdx.x;
        int r = e >> 6, c = e & 63;
        tile[r][c] = W[(size_t)(ti * 64 + r) * 128 + tj * 64 + c];
    }
    __syncthreads();
#pragma unroll
    for (int i = 0; i < 16; ++i) {
        int e = i * 256 + threadIdx.x;
        int r = e >> 6, c = e & 63;
        wt[(size_t)m * 16384 + (size_t)(tj * 64 + r) * 128 + ti * 64 + c] = f2b(tile[c][r]);
    }
}

// ---------------- MFMA GEMM: W staged in LDS (swizzled), 2 node-groups/wave ---
// Swapped operands: D col=lane&15 -> NODE, D row=4*(lane>>4)+reg -> feats.
// The REUSED operand is W (every wave reads all 32KB) -> stage W in LDS and
// read via ds_read_b128 (12cyc) instead of 48 latency-chained L2 loads/wave.
// x/p have zero reuse -> direct global->VGPR. W buffer re-staged per pass.
// XOR swizzle byte^=(row&7)<<4 kills the 16-way stride-256B read conflict.
// MODE 0: h  = bf16(relu(x@W1+bias))           -> yh SLICE-MAJOR [ft][NP][16]
// MODE 1: x' = relu(x@W1 + p@W2 + bias)        -> yx bf16 row-major
//         h' = bf16(relu(x'@Wnt + bias_n))     -> yh SLICE-MAJOR
// MODE 2: x' -> yf f32 row-major (final out)
// p input is SLICE-MAJOR [s][N_NODES][16].
template <int MODE, bool AF32>
__global__ __launch_bounds__(256, 2) void gemm_kernel(
    const void* __restrict__ xv, const unsigned short* __restrict__ p,
    const unsigned short* __restrict__ W1t, const unsigned short* __restrict__ W2t,
    const float* __restrict__ bias,
    const unsigned short* __restrict__ Wnt, const float* __restrict__ bias_n,
    float* __restrict__ yf, unsigned short* __restrict__ yx,
    unsigned short* __restrict__ yh) {
    __shared__ unsigned short wlds[128 * FEAT];                    // 32 KB W tile
    __shared__ unsigned short xs[(MODE == 1) ? 128 * FEAT : 16];   // x' exchange
    const int tid = threadIdx.x;
    const int wv = tid >> 6;
    const int lane = tid & 63;
    const int l15 = lane & 15;
    const int lhi = lane >> 4;
    const int n0 = blockIdx.x * 128;
    const int fsub = 4 * lhi;

    int nrow[2], nglob[2], nclamp[2];
#pragma unroll
    for (int g = 0; g < 2; ++g) {
        nrow[g] = (2 * wv + g) * 16 + l15;
        nglob[g] = n0 + nrow[g];
        nclamp[g] = (nglob[g] < N_NODES) ? nglob[g] : (N_NODES - 1);
    }

    // ---- issue x (and p) loads: direct global->VGPR, all in flight ----
    bf16x8 xf[2][4];
    if (AF32) {
        const float* x = (const float*)xv;
#pragma unroll
        for (int g = 0; g < 2; ++g)
#pragma unroll
            for (int kk = 0; kk < 4; ++kk) {
                const float4* gp = (const float4*)(x + (size_t)nclamp[g] * FEAT + kk * 32 + lhi * 8);
                float4 v0 = gp[0], v1 = gp[1];
                unsigned short hh[8];
                hh[0] = f2b(v0.x); hh[1] = f2b(v0.y); hh[2] = f2b(v0.z); hh[3] = f2b(v0.w);
                hh[4] = f2b(v1.x); hh[5] = f2b(v1.y); hh[6] = f2b(v1.z); hh[7] = f2b(v1.w);
                xf[g][kk] = *(bf16x8*)hh;
            }
    } else {
        const unsigned short* xb = (const unsigned short*)xv;
#pragma unroll
        for (int g = 0; g < 2; ++g)
#pragma unroll
            for (int kk = 0; kk < 4; ++kk)
                xf[g][kk] = *(const bf16x8*)(xb + (size_t)nclamp[g] * FEAT + kk * 32 + lhi * 8);
    }
    bf16x8 pf[2][4];
    if (MODE >= 1) {
#pragma unroll
        for (int g = 0; g < 2; ++g)
#pragma unroll
            for (int kk = 0; kk < 4; ++kk) {
                int f0 = kk * 32 + lhi * 8;
                int sl = f0 >> 4;
                int off = f0 & 15;
                pf[g][kk] = *(const bf16x8*)(p + ((size_t)sl * N_NODES + nclamp[g]) * 16 + off);
            }
    }

    // ---- W staging: 8 uint4/thread, XOR-swizzled ----
    auto stage_w = [&](const unsigned short* Wt) {
#pragma unroll
        for (int it = 0; it < 8; ++it) {
            int idx = it * 256 + tid;           // uint4 index 0..2047
            int row = idx >> 4;
            int byte = (idx * 16) ^ ((row & 7) << 4);
            *(uint4*)((char*)wlds + byte) = *(const uint4*)(Wt + idx * 8);
        }
    };

    f32x4 acc[2][8];
    auto clear_acc = [&]() {
#pragma unroll
        for (int g = 0; g < 2; ++g)
#pragma unroll
            for (int q = 0; q < 8; ++q) acc[g][q] = (f32x4)(0.f);
    };
    auto mfma_pass = [&](bf16x8 (&xin)[2][4]) {
#pragma unroll
        for (int ft = 0; ft < 8; ++ft) {
            const int row = ft * 16 + l15;
#pragma unroll
            for (int kk = 0; kk < 4; ++kk) {
                int byte = (row * 256 + (kk * 32 + lhi * 8) * 2) ^ ((row & 7) << 4);
                bf16x8 wfrag = *(const bf16x8*)((const char*)wlds + byte);
                acc[0][ft] = __builtin_amdgcn_mfma_f32_16x16x32_bf16(wfrag, xin[0][kk], acc[0][ft], 0, 0, 0);
                acc[1][ft] = __builtin_amdgcn_mfma_f32_16x16x32_bf16(wfrag, xin[1][kk], acc[1][ft], 0, 0, 0);
            }
        }
    };

    clear_acc();
    stage_w(W1t);
    __syncthreads();
    mfma_pass(xf);

    if (MODE >= 1) {
        __syncthreads();
        stage_w(W2t);
        __syncthreads();
        mfma_pass(pf);
    }

    // ---- epilogue 1: bias + relu; wide stores; x' into wave-private LDS band --
#pragma unroll
    for (int g = 0; g < 2; ++g) {
#pragma unroll
        for (int ft = 0; ft < 8; ++ft) {
            float4 bv = ((const float4*)bias)[ft * 4 + lhi];
            float v0 = fmaxf(acc[g][ft][0] + bv.x, 0.f);
            float v1 = fmaxf(acc[g][ft][1] + bv.y, 0.f);
            float v2 = fmaxf(acc[g][ft][2] + bv.z, 0.f);
            float v3 = fmaxf(acc[g][ft][3] + bv.w, 0.f);
            uint2 pk = make_uint2((unsigned)f2b(v0) | ((unsigned)f2b(v1) << 16),
                                  (unsigned)f2b(v2) | ((unsigned)f2b(v3) << 16));
            if (MODE == 0) {
                if (nglob[g] < N_NODES)
                    *(uint2*)(yh + ((size_t)ft * NP + nglob[g]) * 16 + fsub) = pk;
            } else if (MODE == 2) {
                if (nglob[g] < N_NODES)
                    *(float4*)(yf + (size_t)nglob[g] * FEAT + ft * 16 + fsub) =
                        make_float4(v0, v1, v2, v3);
            } else {
                if (nglob[g] < N_NODES)
                    *(uint2*)(yx + (size_t)nglob[g] * FEAT + ft * 16 + fsub) = pk;
                int byte = (nrow[g] * 256 + (ft * 16 + fsub) * 2) ^ ((nrow[g] & 7) << 4);
                *(uint2*)((char*)xs + byte) = pk;   // own band only
            }
        }
    }

    // ---- pass 3 (MODE 1): h' = relu(x' @ Wnt + bias_n) -> slice-major ----
    if (MODE == 1) {
        __syncthreads();          // all waves done reading wlds (W2)
        stage_w(Wnt);
        __syncthreads();
        bf16x8 xf2[2][4];
#pragma unroll
        for (int g = 0; g < 2; ++g)
#pragma unroll
            for (int kk = 0; kk < 4; ++kk) {
                int byte = (nrow[g] * 256 + (kk * 32 + lhi * 8) * 2) ^ ((nrow[g] & 7) << 4);
                xf2[g][kk] = *(const bf16x8*)((const char*)xs + byte);
            }
        clear_acc();
        mfma_pass(xf2);
#pragma unroll
        for (int g = 0; g < 2; ++g) {
#pragma unroll
            for (int ft = 0; ft < 8; ++ft) {
                float4 bv = ((const float4*)bias_n)[ft * 4 + lhi];
                float v0 = fmaxf(acc[g][ft][0] + bv.x, 0.f);
                float v1 = fmaxf(acc[g][ft][1] + bv.y, 0.f);
                float v2 = fmaxf(acc[g][ft][2] + bv.z, 0.f);
                float v3 = fmaxf(acc[g][ft][3] + bv.w, 0.f);
                uint2 pk = make_uint2((unsigned)f2b(v0) | ((unsigned)f2b(v1) << 16),
                                      (unsigned)f2b(v2) | ((unsigned)f2b(v3) << 16));
                if (nglob[g] < N_NODES)
                    *(uint2*)(yh + ((size_t)ft * NP + nglob[g]) * 16 + fsub) = pk;
            }
        }
    }
}

// ------- segment max: XCD-pinned slices, index-prefetch, 32-bit addressing ----
__global__ __launch_bounds__(256) void seg_max_kernel(
    const unsigned short* __restrict__ hs, const int* __restrict__ row_ptr,
    const int* __restrict__ edge_src, unsigned short* __restrict__ pooled) {
    const int s = blockIdx.x & 7;
    const int g = blockIdx.x >> 3;            // node group of 16
    const int wv = threadIdx.x >> 6;
    const int lane = threadIdx.x & 63;
    const int qn = lane >> 4;                 // node-in-wave 0..3
    const int slot = (lane >> 1) & 7;         // edge slot 0..7
    const int f = lane & 1;                   // feat half 0..1 (8 feats = 16B)
    int node = g * 16 + wv * 4 + qn;
    const bool valid = node < N_NODES;
    node = valid ? node : N_NODES - 1;
    const char* hb = (const char*)(hs + (size_t)s * NP * 16);   // uniform base
    const unsigned fo = (unsigned)f * 16u;

    const int start = row_ptr[node];
    const int end = row_ptr[node + 1];
    unsigned int a0 = 0u, a1 = 0u, a2 = 0u, a3 = 0u;   // packed 8x bf16 (>=0)

    int i = start + slot;
    int e0 = (i < end) ? edge_src[i] : N_NODES;        // N_NODES = zero row
    int e1 = (i + 8 < end) ? edge_src[i + 8] : N_NODES;
    for (; i < end; i += 16) {
        int ne0 = (i + 16 < end) ? edge_src[i + 16] : N_NODES;
        int ne1 = (i + 24 < end) ? edge_src[i + 24] : N_NODES;
        const uint4 v0 = *(const uint4*)(hb + ((unsigned)e0 * 32u + fo));
        const uint4 v1 = *(const uint4*)(hb + ((unsigned)e1 * 32u + fo));
        a0 = pkmax(a0, v0.x); a1 = pkmax(a1, v0.y);
        a2 = pkmax(a2, v0.z); a3 = pkmax(a3, v0.w);
        a0 = pkmax(a0, v1.x); a1 = pkmax(a1, v1.y);
        a2 = pkmax(a2, v1.z); a3 = pkmax(a3, v1.w);
        e0 = ne0; e1 = ne1;
    }
#pragma unroll
    for (int off = 2; off <= 8; off <<= 1) {
        a0 = pkmax(a0, __shfl_xor(a0, off, 64));
        a1 = pkmax(a1, __shfl_xor(a1, off, 64));
        a2 = pkmax(a2, __shfl_xor(a2, off, 64));
        a3 = pkmax(a3, __shfl_xor(a3, off, 64));
    }
    if (slot == 0 && valid) {
        char* pb = (char*)(pooled + (size_t)s * N_NODES * 16);
        *(uint4*)(pb + ((unsigned)node * 32u + fo)) = make_uint4(a0, a1, a2, a3);
    }
}

// ---------------- launch ----------------
// ws (~148 MB < proven 161): edge_src 6.4 | ebuf 12.8 | deg 0.4 | bkt_cnt 1K |
// row_ptr 0.4 | blk_sums 2K | bkt_start 1K | bkt_cursor 1K | wt 0.39 |
// bufH 25.6+2K (slice-major PADDED) | bufP 25.6 (slice-major) | bufX0/X1 25.6 ea
// x chain: feats(f32) -> X0 -> X1 -> X0 -> d_out(f32)

extern "C" void kernel_launch(void* const* d_in, const int* in_sizes, int n_in,
                              void* d_out, int out_size, void* d_ws, size_t ws_size,
                              hipStream_t stream) {
    const float* feats = (const float*)d_in[0];
    const float* Wp = (const float*)d_in[1];
    const float* bp = (const float*)d_in[2];
    const float* Ws = (const float*)d_in[3];
    const float* Wn = (const float*)d_in[4];
    const float* bb = (const float*)d_in[5];
    const int* src = (const int*)d_in[6];
    const int* dst = (const int*)d_in[7];
    float* out = (float*)d_out;

    const size_t NF = (size_t)N_NODES * FEAT;
    char* ws = (char*)d_ws;
    int* edge_src = (int*)ws;    ws += (size_t)N_EDGES * sizeof(int);
    int2* ebuf = (int2*)ws;      ws += (size_t)N_EDGES * sizeof(int2);
    int* deg = (int*)ws;         ws += (size_t)N_NODES * sizeof(int);
    int* bkt_cnt = (int*)ws;     ws += 256 * sizeof(int);
    int* row_ptr = (int*)ws;     ws += (size_t)(N_NODES + 4) * sizeof(int);
    int* blk_sums = (int*)ws;    ws += 512 * sizeof(int);
    int* bkt_start = (int*)ws;   ws += 256 * sizeof(int);
    int* bkt_cursor = (int*)ws;  ws += 256 * sizeof(int);
    unsigned short* wt = (unsigned short*)ws;    ws += (size_t)12 * 16384 * sizeof(unsigned short);
    unsigned short* bufH = (unsigned short*)ws;  ws += (size_t)8 * NP * 16 * sizeof(unsigned short);
    unsigned short* bufP = (unsigned short*)ws;  ws += NF * sizeof(unsigned short);
    unsigned short* bufX0 = (unsigned short*)ws; ws += NF * sizeof(unsigned short);
    unsigned short* bufX1 = (unsigned short*)ws;

    // CSR build (deg & bkt_cnt adjacent -> single memset)
    hipMemsetAsync(deg, 0, ((size_t)N_NODES + 256) * sizeof(int), stream);
    count_deg_kernel<<<N_P1_BLKS, 256, 0, stream>>>(dst, deg, bkt_cnt);
    blk_sum_kernel<<<N_SCAN_BLKS, SCAN_BLK, 0, stream>>>(deg, blk_sums);
    scan_all_kernel<<<1, 512, 0, stream>>>(blk_sums, bkt_cnt, bkt_start, bkt_cursor);
    write_rowptr_kernel<<<N_SCAN_BLKS, SCAN_BLK, 0, stream>>>(deg, blk_sums, row_ptr);
    bucket_scatter_kernel<<<N_P1_BLKS, 256, 0, stream>>>(src, dst, bkt_cursor, ebuf);
    csr_scatter_kernel<<<NBKT, 256, 0, stream>>>(ebuf, bkt_start, row_ptr, edge_src);
    convert_wt_kernel<<<49, 256, 0, stream>>>(Wp, Ws, Wn, wt, bufH);

    const int seg_grid = ((N_NODES + 15) / 16) * 8;   // 6250 groups x 8 slices

    const unsigned short* xb[LAYERS] = {nullptr, bufX0, bufX1, bufX0};
    unsigned short* xo[LAYERS] = {bufX0, bufX1, bufX0, nullptr};

    // layer 0 h_pool
    gemm_kernel<0, true><<<GEMM_GRID, 256, 0, stream>>>(
        feats, nullptr, wt, nullptr, bp, nullptr, nullptr, nullptr, nullptr, bufH);

    for (int l = 0; l < LAYERS; ++l) {
        const unsigned short* WsT = wt + (size_t)(4 + l) * 16384;
        const unsigned short* WnT = wt + (size_t)(8 + l) * 16384;
        const float* bl = bb + (size_t)l * FEAT;

        seg_max_kernel<<<seg_grid, 256, 0, stream>>>(bufH, row_ptr, edge_src, bufP);

        if (l == 0) {
            gemm_kernel<1, true><<<GEMM_GRID, 256, 0, stream>>>(
                feats, bufP, WsT, WnT, bl, wt + (size_t)(l + 1) * 16384,
                bp + (size_t)(l + 1) * FEAT, nullptr, xo[l], bufH);
        } else if (l < LAYERS - 1) {
            gemm_kernel<1, false><<<GEMM_GRID, 256, 0, stream>>>(
                xb[l], bufP, WsT, WnT, bl, wt + (size_t)(l + 1) * 16384,
                bp + (size_t)(l + 1) * FEAT, nullptr, xo[l], bufH);
        } else {
            gemm_kernel<2, false><<<GEMM_GRID, 256, 0, stream>>>(
                xb[l], bufP, WsT, WnT, bl, nullptr, nullptr, out, nullptr, nullptr);
        }
    }
}

// Round 16
// 575.153 us; speedup vs baseline: 1.6971x; 1.0117x over previous
//
#include <hip/hip_runtime.h>

#define N_NODES 100000
#define NP (N_NODES + 8)                                   // padded (8 zero rows/slice)
#define N_EDGES 1600000
#define FEAT 128
#define LAYERS 4
#define SCAN_BLK 256
#define N_SCAN_BLKS ((N_NODES + SCAN_BLK - 1) / SCAN_BLK)  // 391
#define NBKT ((N_NODES + 511) >> 9)                        // 196 buckets x 512 nodes
#define P1_CHUNK 4096
#define N_P1_BLKS ((N_EDGES + P1_CHUNK - 1) / P1_CHUNK)    // 391
#define GEMM_GRID ((N_NODES + 127) / 128)                  // 782 (128 nodes/block)

typedef __attribute__((ext_vector_type(8))) short bf16x8;
typedef __attribute__((ext_vector_type(4))) float f32x4;

__device__ __forceinline__ unsigned short f2b(float f) {   // f32 -> bf16 RNE
    union { float f; unsigned int u; } v; v.f = f;
    unsigned int u = v.u;
    return (unsigned short)((u + 0x7fffu + ((u >> 16) & 1u)) >> 16);
}

// packed max of 2x bf16 (valid for non-negative bf16: bit pattern is monotone)
__device__ __forceinline__ unsigned int pkmax(unsigned int a, unsigned int b) {
    unsigned int r;
    asm("v_pk_max_u16 %0, %1, %2" : "=v"(r) : "v"(a), "v"(b));
    return r;
}

// ---------------- CSR build (bucketed) ----------------

__global__ __launch_bounds__(256) void count_deg_kernel(const int* __restrict__ dst,
                                                        int* __restrict__ deg,
                                                        int* __restrict__ bkt_cnt) {
    __shared__ int h[NBKT];
    for (int i = threadIdx.x; i < NBKT; i += 256) h[i] = 0;
    __syncthreads();
    const int base = blockIdx.x * P1_CHUNK;
    for (int i = threadIdx.x; i < P1_CHUNK; i += 256) {
        int e = base + i;
        if (e < N_EDGES) {
            int d = dst[e];
            atomicAdd(&deg[d], 1);
            atomicAdd(&h[d >> 9], 1);
        }
    }
    __syncthreads();
    for (int i = threadIdx.x; i < NBKT; i += 256)
        if (h[i]) atomicAdd(&bkt_cnt[i], h[i]);
}

__global__ __launch_bounds__(SCAN_BLK) void blk_sum_kernel(const int* __restrict__ deg,
                                                           int* __restrict__ blk_sums) {
    int i = blockIdx.x * SCAN_BLK + threadIdx.x;
    int v = (i < N_NODES) ? deg[i] : 0;
#pragma unroll
    for (int off = 32; off; off >>= 1) v += __shfl_down(v, off, 64);
    __shared__ int ws_[SCAN_BLK / 64];
    if ((threadIdx.x & 63) == 0) ws_[threadIdx.x >> 6] = v;
    __syncthreads();
    if (threadIdx.x == 0) {
        int s = 0;
#pragma unroll
        for (int w = 0; w < SCAN_BLK / 64; ++w) s += ws_[w];
        blk_sums[blockIdx.x] = s;
    }
}

__global__ __launch_bounds__(512) void scan_all_kernel(int* __restrict__ blk_sums,
                                                       const int* __restrict__ bkt_cnt,
                                                       int* __restrict__ bkt_start,
                                                       int* __restrict__ bkt_cursor) {
    __shared__ int s[512];
    __shared__ int b[256];
    const int t = threadIdx.x;
    s[t] = (t < N_SCAN_BLKS) ? blk_sums[t] : 0;
    if (t < 256) b[t] = (t < NBKT) ? bkt_cnt[t] : 0;
    __syncthreads();
    for (int off = 1; off < 512; off <<= 1) {
        int v = (t >= off) ? s[t - off] : 0;
        __syncthreads();
        s[t] += v;
        __syncthreads();
    }
    for (int off = 1; off < 256; off <<= 1) {
        int v = (t < 256 && t >= off) ? b[t - off] : 0;
        __syncthreads();
        if (t < 256) b[t] += v;
        __syncthreads();
    }
    if (t < N_SCAN_BLKS) blk_sums[t] = (t == 0) ? 0 : s[t - 1];
    if (t < NBKT) {
        int st = (t == 0) ? 0 : b[t - 1];
        bkt_start[t] = st;
        bkt_cursor[t] = st;
    }
    if (t == 0) bkt_start[NBKT] = N_EDGES;
}

__global__ __launch_bounds__(SCAN_BLK) void write_rowptr_kernel(
    const int* __restrict__ deg, const int* __restrict__ blk_off,
    int* __restrict__ row_ptr) {
    __shared__ int s[SCAN_BLK];
    const int t = threadIdx.x;
    const int i = blockIdx.x * SCAN_BLK + t;
    int v = (i < N_NODES) ? deg[i] : 0;
    s[t] = v;
    __syncthreads();
    for (int off = 1; off < SCAN_BLK; off <<= 1) {
        int u = (t >= off) ? s[t - off] : 0;
        __syncthreads();
        s[t] += u;
        __syncthreads();
    }
    int excl = s[t] - v + blk_off[blockIdx.x];
    if (i < N_NODES) row_ptr[i] = excl;
    if (i == 0) row_ptr[N_NODES] = N_EDGES;
}

__global__ __launch_bounds__(256) void bucket_scatter_kernel(
    const int* __restrict__ src, const int* __restrict__ dst,
    int* __restrict__ bkt_cursor, int2* __restrict__ ebuf) {
    __shared__ int h[NBKT], base[NBKT], cur[NBKT];
    for (int i = threadIdx.x; i < NBKT; i += 256) h[i] = 0;
    __syncthreads();
    const int b0 = blockIdx.x * P1_CHUNK;
    for (int i = threadIdx.x; i < P1_CHUNK; i += 256) {
        int e = b0 + i;
        if (e < N_EDGES) atomicAdd(&h[dst[e] >> 9], 1);
    }
    __syncthreads();
    for (int i = threadIdx.x; i < NBKT; i += 256) {
        cur[i] = 0;
        base[i] = h[i] ? atomicAdd(&bkt_cursor[i], h[i]) : 0;
    }
    __syncthreads();
    for (int i = threadIdx.x; i < P1_CHUNK; i += 256) {
        int e = b0 + i;
        if (e < N_EDGES) {
            int d = dst[e];
            int bk = d >> 9;
            int pos = base[bk] + atomicAdd(&cur[bk], 1);
            ebuf[pos] = make_int2(src[e], d);
        }
    }
}

__global__ __launch_bounds__(256) void csr_scatter_kernel(
    const int2* __restrict__ ebuf, const int* __restrict__ bkt_start,
    const int* __restrict__ row_ptr, int* __restrict__ edge_src) {
    __shared__ int cur[512];
    const int bk = blockIdx.x;
    const int n0 = bk << 9;
    for (int i = threadIdx.x; i < 512; i += 256) {
        int n = n0 + i;
        cur[i] = (n < N_NODES) ? row_ptr[n] : 0;
    }
    __syncthreads();
    const int s = bkt_start[bk], e = bkt_start[bk + 1];
    for (int i = s + threadIdx.x; i < e; i += 256) {
        int2 ed = ebuf[i];
        int pos = atomicAdd(&cur[ed.y - n0], 1);
        edge_src[pos] = ed.x;
    }
}

// ------- weight convert + bufH pad-row zeroing (block 48) -------
__global__ __launch_bounds__(256) void convert_wt_kernel(
    const float* __restrict__ Wp, const float* __restrict__ Ws,
    const float* __restrict__ Wn, unsigned short* __restrict__ wt,
    unsigned short* __restrict__ hpad) {
    if (blockIdx.x == 48) {
        for (int idx = threadIdx.x; idx < 8 * 8 * 16; idx += 256) {
            int s = idx >> 7;
            int rc = idx & 127;
            hpad[((size_t)s * NP + N_NODES) * 16 + rc] = 0;
        }
        return;
    }
    __shared__ float tile[64][65];
    const int m = blockIdx.x >> 2;
    const int tij = blockIdx.x & 3;
    const int ti = tij >> 1, tj = tij & 1;
    const float* W = (m < 4) ? Wp + (size_t)m * 16384
                   : (m < 8) ? Ws + (size_t)(m - 4) * 16384
                             : Wn + (size_t)(m - 8) * 16384;
#pragma unroll
    for (int i = 0; i < 16; ++i) {
        int e = i * 256 + threadIdx.x;
        int r = e >> 6, c = e & 63;
        tile[r][c] = W[(size_t)(ti * 64 + r) * 128 + tj * 64 + c];
    }
    __syncthreads();
#pragma unroll
    for (int i = 0; i < 16; ++i) {
        int e = i * 256 + threadIdx.x;
        int r = e >> 6, c = e & 63;
        wt[(size_t)m * 16384 + (size_t)(tj * 64 + r) * 128 + ti * 64 + c] = f2b(tile[c][r]);
    }
}

// ---------------- MFMA GEMM: W staged in LDS (swizzled), 2 node-groups/wave ---
// (R15-proven structure, unchanged)
template <int MODE, bool AF32>
__global__ __launch_bounds__(256, 2) void gemm_kernel(
    const void* __restrict__ xv, const unsigned short* __restrict__ p,
    const unsigned short* __restrict__ W1t, const unsigned short* __restrict__ W2t,
    const float* __restrict__ bias,
    const unsigned short* __restrict__ Wnt, const float* __restrict__ bias_n,
    float* __restrict__ yf, unsigned short* __restrict__ yx,
    unsigned short* __restrict__ yh) {
    __shared__ unsigned short wlds[128 * FEAT];                    // 32 KB W tile
    __shared__ unsigned short xs[(MODE == 1) ? 128 * FEAT : 16];   // x' exchange
    const int tid = threadIdx.x;
    const int wv = tid >> 6;
    const int lane = tid & 63;
    const int l15 = lane & 15;
    const int lhi = lane >> 4;
    const int n0 = blockIdx.x * 128;
    const int fsub = 4 * lhi;

    int nrow[2], nglob[2], nclamp[2];
#pragma unroll
    for (int g = 0; g < 2; ++g) {
        nrow[g] = (2 * wv + g) * 16 + l15;
        nglob[g] = n0 + nrow[g];
        nclamp[g] = (nglob[g] < N_NODES) ? nglob[g] : (N_NODES - 1);
    }

    bf16x8 xf[2][4];
    if (AF32) {
        const float* x = (const float*)xv;
#pragma unroll
        for (int g = 0; g < 2; ++g)
#pragma unroll
            for (int kk = 0; kk < 4; ++kk) {
                const float4* gp = (const float4*)(x + (size_t)nclamp[g] * FEAT + kk * 32 + lhi * 8);
                float4 v0 = gp[0], v1 = gp[1];
                unsigned short hh[8];
                hh[0] = f2b(v0.x); hh[1] = f2b(v0.y); hh[2] = f2b(v0.z); hh[3] = f2b(v0.w);
                hh[4] = f2b(v1.x); hh[5] = f2b(v1.y); hh[6] = f2b(v1.z); hh[7] = f2b(v1.w);
                xf[g][kk] = *(bf16x8*)hh;
            }
    } else {
        const unsigned short* xb = (const unsigned short*)xv;
#pragma unroll
        for (int g = 0; g < 2; ++g)
#pragma unroll
            for (int kk = 0; kk < 4; ++kk)
                xf[g][kk] = *(const bf16x8*)(xb + (size_t)nclamp[g] * FEAT + kk * 32 + lhi * 8);
    }
    bf16x8 pf[2][4];
    if (MODE >= 1) {
#pragma unroll
        for (int g = 0; g < 2; ++g)
#pragma unroll
            for (int kk = 0; kk < 4; ++kk) {
                int f0 = kk * 32 + lhi * 8;
                int sl = f0 >> 4;
                int off = f0 & 15;
                pf[g][kk] = *(const bf16x8*)(p + ((size_t)sl * N_NODES + nclamp[g]) * 16 + off);
            }
    }

    auto stage_w = [&](const unsigned short* Wt) {
#pragma unroll
        for (int it = 0; it < 8; ++it) {
            int idx = it * 256 + tid;           // uint4 index 0..2047
            int row = idx >> 4;
            int byte = (idx * 16) ^ ((row & 7) << 4);
            *(uint4*)((char*)wlds + byte) = *(const uint4*)(Wt + idx * 8);
        }
    };

    f32x4 acc[2][8];
    auto clear_acc = [&]() {
#pragma unroll
        for (int g = 0; g < 2; ++g)
#pragma unroll
            for (int q = 0; q < 8; ++q) acc[g][q] = (f32x4)(0.f);
    };
    auto mfma_pass = [&](bf16x8 (&xin)[2][4]) {
#pragma unroll
        for (int ft = 0; ft < 8; ++ft) {
            const int row = ft * 16 + l15;
#pragma unroll
            for (int kk = 0; kk < 4; ++kk) {
                int byte = (row * 256 + (kk * 32 + lhi * 8) * 2) ^ ((row & 7) << 4);
                bf16x8 wfrag = *(const bf16x8*)((const char*)wlds + byte);
                acc[0][ft] = __builtin_amdgcn_mfma_f32_16x16x32_bf16(wfrag, xin[0][kk], acc[0][ft], 0, 0, 0);
                acc[1][ft] = __builtin_amdgcn_mfma_f32_16x16x32_bf16(wfrag, xin[1][kk], acc[1][ft], 0, 0, 0);
            }
        }
    };

    clear_acc();
    stage_w(W1t);
    __syncthreads();
    mfma_pass(xf);

    if (MODE >= 1) {
        __syncthreads();
        stage_w(W2t);
        __syncthreads();
        mfma_pass(pf);
    }

#pragma unroll
    for (int g = 0; g < 2; ++g) {
#pragma unroll
        for (int ft = 0; ft < 8; ++ft) {
            float4 bv = ((const float4*)bias)[ft * 4 + lhi];
            float v0 = fmaxf(acc[g][ft][0] + bv.x, 0.f);
            float v1 = fmaxf(acc[g][ft][1] + bv.y, 0.f);
            float v2 = fmaxf(acc[g][ft][2] + bv.z, 0.f);
            float v3 = fmaxf(acc[g][ft][3] + bv.w, 0.f);
            uint2 pk = make_uint2((unsigned)f2b(v0) | ((unsigned)f2b(v1) << 16),
                                  (unsigned)f2b(v2) | ((unsigned)f2b(v3) << 16));
            if (MODE == 0) {
                if (nglob[g] < N_NODES)
                    *(uint2*)(yh + ((size_t)ft * NP + nglob[g]) * 16 + fsub) = pk;
            } else if (MODE == 2) {
                if (nglob[g] < N_NODES)
                    *(float4*)(yf + (size_t)nglob[g] * FEAT + ft * 16 + fsub) =
                        make_float4(v0, v1, v2, v3);
            } else {
                if (nglob[g] < N_NODES)
                    *(uint2*)(yx + (size_t)nglob[g] * FEAT + ft * 16 + fsub) = pk;
                int byte = (nrow[g] * 256 + (ft * 16 + fsub) * 2) ^ ((nrow[g] & 7) << 4);
                *(uint2*)((char*)xs + byte) = pk;   // own band only
            }
        }
    }

    if (MODE == 1) {
        __syncthreads();          // all waves done reading wlds (W2)
        stage_w(Wnt);
        __syncthreads();
        bf16x8 xf2[2][4];
#pragma unroll
        for (int g = 0; g < 2; ++g)
#pragma unroll
            for (int kk = 0; kk < 4; ++kk) {
                int byte = (nrow[g] * 256 + (kk * 32 + lhi * 8) * 2) ^ ((nrow[g] & 7) << 4);
                xf2[g][kk] = *(const bf16x8*)((const char*)xs + byte);
            }
        clear_acc();
        mfma_pass(xf2);
#pragma unroll
        for (int g = 0; g < 2; ++g) {
#pragma unroll
            for (int ft = 0; ft < 8; ++ft) {
                float4 bv = ((const float4*)bias_n)[ft * 4 + lhi];
                float v0 = fmaxf(acc[g][ft][0] + bv.x, 0.f);
                float v1 = fmaxf(acc[g][ft][1] + bv.y, 0.f);
                float v2 = fmaxf(acc[g][ft][2] + bv.z, 0.f);
                float v3 = fmaxf(acc[g][ft][3] + bv.w, 0.f);
                uint2 pk = make_uint2((unsigned)f2b(v0) | ((unsigned)f2b(v1) << 16),
                                      (unsigned)f2b(v2) | ((unsigned)f2b(v3) << 16));
                if (nglob[g] < N_NODES)
                    *(uint2*)(yh + ((size_t)ft * NP + nglob[g]) * 16 + fsub) = pk;
            }
        }
    }
}

// ------- segment max: XCD-pinned slices, 2 nodes/quarter-wave (dual chains) ---
// h slice-major PADDED: hs[s][NP][16]; rows N_NODES.. are zeros (pkmax identity).
// Each quarter-wave (8 slots x 2 f) handles TWO nodes (qn, qn+4): both nodes'
// row_ptr/index/gather chains issue interleaved -> 2x in-flight memory per wave.
// Clamped indices keep the loop body branch-free; exec-mask handles ragged exit
// (done-node gathers hit the zero row = pkmax identity).
__global__ __launch_bounds__(256) void seg_max_kernel(
    const unsigned short* __restrict__ hs, const int* __restrict__ row_ptr,
    const int* __restrict__ edge_src, unsigned short* __restrict__ pooled) {
    const int s = blockIdx.x & 7;
    const int g = blockIdx.x >> 3;            // node group of 32
    const int wv = threadIdx.x >> 6;
    const int lane = threadIdx.x & 63;
    const int qn = lane >> 4;                 // quarter 0..3
    const int slot = (lane >> 1) & 7;         // edge slot 0..7
    const int f = lane & 1;                   // feat half 0..1 (8 feats = 16B)
    const char* hb = (const char*)(hs + (size_t)s * NP * 16);   // uniform base
    const unsigned fo = (unsigned)f * 16u;
    const int nbase = g * 32 + wv * 8;

    int nA = nbase + qn, nB = nbase + qn + 4;
    const bool vA = nA < N_NODES, vB = nB < N_NODES;
    nA = vA ? nA : N_NODES - 1;
    nB = vB ? nB : N_NODES - 1;

    const int sA = row_ptr[nA], eA = row_ptr[nA + 1];
    const int sB = row_ptr[nB], eB = row_ptr[nB + 1];

    unsigned aA0 = 0u, aA1 = 0u, aA2 = 0u, aA3 = 0u;
    unsigned aB0 = 0u, aB1 = 0u, aB2 = 0u, aB3 = 0u;

    int iA = sA + slot, iB = sB + slot;
    int eA0 = (iA < eA) ? edge_src[iA] : N_NODES;
    int eA1 = (iA + 8 < eA) ? edge_src[iA + 8] : N_NODES;
    int eB0 = (iB < eB) ? edge_src[iB] : N_NODES;
    int eB1 = (iB + 8 < eB) ? edge_src[iB + 8] : N_NODES;

    while (iA < eA || iB < eB) {
        // prefetch next trip's indices (hides under this trip's gathers)
        int pA0 = (iA + 16 < eA) ? edge_src[iA + 16] : N_NODES;
        int pA1 = (iA + 24 < eA) ? edge_src[iA + 24] : N_NODES;
        int pB0 = (iB + 16 < eB) ? edge_src[iB + 16] : N_NODES;
        int pB1 = (iB + 24 < eB) ? edge_src[iB + 24] : N_NODES;
        const uint4 vA0 = *(const uint4*)(hb + ((unsigned)eA0 * 32u + fo));
        const uint4 vA1 = *(const uint4*)(hb + ((unsigned)eA1 * 32u + fo));
        const uint4 vB0 = *(const uint4*)(hb + ((unsigned)eB0 * 32u + fo));
        const uint4 vB1 = *(const uint4*)(hb + ((unsigned)eB1 * 32u + fo));
        aA0 = pkmax(aA0, vA0.x); aA1 = pkmax(aA1, vA0.y);
        aA2 = pkmax(aA2, vA0.z); aA3 = pkmax(aA3, vA0.w);
        aA0 = pkmax(aA0, vA1.x); aA1 = pkmax(aA1, vA1.y);
        aA2 = pkmax(aA2, vA1.z); aA3 = pkmax(aA3, vA1.w);
        aB0 = pkmax(aB0, vB0.x); aB1 = pkmax(aB1, vB0.y);
        aB2 = pkmax(aB2, vB0.z); aB3 = pkmax(aB3, vB0.w);
        aB0 = pkmax(aB0, vB1.x); aB1 = pkmax(aB1, vB1.y);
        aB2 = pkmax(aB2, vB1.z); aB3 = pkmax(aB3, vB1.w);
        iA += 16; iB += 16;
        eA0 = pA0; eA1 = pA1; eB0 = pB0; eB1 = pB1;
    }
    // reduce across the 8 slots (lane bits 1..3)
#pragma unroll
    for (int off = 2; off <= 8; off <<= 1) {
        aA0 = pkmax(aA0, __shfl_xor(aA0, off, 64));
        aA1 = pkmax(aA1, __shfl_xor(aA1, off, 64));
        aA2 = pkmax(aA2, __shfl_xor(aA2, off, 64));
        aA3 = pkmax(aA3, __shfl_xor(aA3, off, 64));
        aB0 = pkmax(aB0, __shfl_xor(aB0, off, 64));
        aB1 = pkmax(aB1, __shfl_xor(aB1, off, 64));
        aB2 = pkmax(aB2, __shfl_xor(aB2, off, 64));
        aB3 = pkmax(aB3, __shfl_xor(aB3, off, 64));
    }
    if (slot == 0) {
        char* pb = (char*)(pooled + (size_t)s * N_NODES * 16);
        if (vA) *(uint4*)(pb + ((unsigned)nA * 32u + fo)) = make_uint4(aA0, aA1, aA2, aA3);
        if (vB) *(uint4*)(pb + ((unsigned)nB * 32u + fo)) = make_uint4(aB0, aB1, aB2, aB3);
    }
}

// ---------------- launch ----------------
// ws (~148 MB < proven 161): edge_src 6.4 | ebuf 12.8 | deg 0.4 | bkt_cnt 1K |
// row_ptr 0.4 | blk_sums 2K | bkt_start 1K | bkt_cursor 1K | wt 0.39 |
// bufH 25.6+2K (slice-major PADDED) | bufP 25.6 (slice-major) | bufX0/X1 25.6 ea
// x chain: feats(f32) -> X0 -> X1 -> X0 -> d_out(f32)

extern "C" void kernel_launch(void* const* d_in, const int* in_sizes, int n_in,
                              void* d_out, int out_size, void* d_ws, size_t ws_size,
                              hipStream_t stream) {
    const float* feats = (const float*)d_in[0];
    const float* Wp = (const float*)d_in[1];
    const float* bp = (const float*)d_in[2];
    const float* Ws = (const float*)d_in[3];
    const float* Wn = (const float*)d_in[4];
    const float* bb = (const float*)d_in[5];
    const int* src = (const int*)d_in[6];
    const int* dst = (const int*)d_in[7];
    float* out = (float*)d_out;

    const size_t NF = (size_t)N_NODES * FEAT;
    char* ws = (char*)d_ws;
    int* edge_src = (int*)ws;    ws += (size_t)N_EDGES * sizeof(int);
    int2* ebuf = (int2*)ws;      ws += (size_t)N_EDGES * sizeof(int2);
    int* deg = (int*)ws;         ws += (size_t)N_NODES * sizeof(int);
    int* bkt_cnt = (int*)ws;     ws += 256 * sizeof(int);
    int* row_ptr = (int*)ws;     ws += (size_t)(N_NODES + 4) * sizeof(int);
    int* blk_sums = (int*)ws;    ws += 512 * sizeof(int);
    int* bkt_start = (int*)ws;   ws += 256 * sizeof(int);
    int* bkt_cursor = (int*)ws;  ws += 256 * sizeof(int);
    unsigned short* wt = (unsigned short*)ws;    ws += (size_t)12 * 16384 * sizeof(unsigned short);
    unsigned short* bufH = (unsigned short*)ws;  ws += (size_t)8 * NP * 16 * sizeof(unsigned short);
    unsigned short* bufP = (unsigned short*)ws;  ws += NF * sizeof(unsigned short);
    unsigned short* bufX0 = (unsigned short*)ws; ws += NF * sizeof(unsigned short);
    unsigned short* bufX1 = (unsigned short*)ws;

    // CSR build (deg & bkt_cnt adjacent -> single memset)
    hipMemsetAsync(deg, 0, ((size_t)N_NODES + 256) * sizeof(int), stream);
    count_deg_kernel<<<N_P1_BLKS, 256, 0, stream>>>(dst, deg, bkt_cnt);
    blk_sum_kernel<<<N_SCAN_BLKS, SCAN_BLK, 0, stream>>>(deg, blk_sums);
    scan_all_kernel<<<1, 512, 0, stream>>>(blk_sums, bkt_cnt, bkt_start, bkt_cursor);
    write_rowptr_kernel<<<N_SCAN_BLKS, SCAN_BLK, 0, stream>>>(deg, blk_sums, row_ptr);
    bucket_scatter_kernel<<<N_P1_BLKS, 256, 0, stream>>>(src, dst, bkt_cursor, ebuf);
    csr_scatter_kernel<<<NBKT, 256, 0, stream>>>(ebuf, bkt_start, row_ptr, edge_src);
    convert_wt_kernel<<<49, 256, 0, stream>>>(Wp, Ws, Wn, wt, bufH);

    const int seg_grid = ((N_NODES + 31) / 32) * 8;   // 3125 groups x 8 slices

    const unsigned short* xb[LAYERS] = {nullptr, bufX0, bufX1, bufX0};
    unsigned short* xo[LAYERS] = {bufX0, bufX1, bufX0, nullptr};

    // layer 0 h_pool
    gemm_kernel<0, true><<<GEMM_GRID, 256, 0, stream>>>(
        feats, nullptr, wt, nullptr, bp, nullptr, nullptr, nullptr, nullptr, bufH);

    for (int l = 0; l < LAYERS; ++l) {
        const unsigned short* WsT = wt + (size_t)(4 + l) * 16384;
        const unsigned short* WnT = wt + (size_t)(8 + l) * 16384;
        const float* bl = bb + (size_t)l * FEAT;

        seg_max_kernel<<<seg_grid, 256, 0, stream>>>(bufH, row_ptr, edge_src, bufP);

        if (l == 0) {
            gemm_kernel<1, true><<<GEMM_GRID, 256, 0, stream>>>(
                feats, bufP, WsT, WnT, bl, wt + (size_t)(l + 1) * 16384,
                bp + (size_t)(l + 1) * FEAT, nullptr, xo[l], bufH);
        } else if (l < LAYERS - 1) {
            gemm_kernel<1, false><<<GEMM_GRID, 256, 0, stream>>>(
                xb[l], bufP, WsT, WnT, bl, wt + (size_t)(l + 1) * 16384,
                bp + (size_t)(l + 1) * FEAT, nullptr, xo[l], bufH);
        } else {
            gemm_kernel<2, false><<<GEMM_GRID, 256, 0, stream>>>(
                xb[l], bufP, WsT, WnT, bl, nullptr, nullptr, out, nullptr, nullptr);
        }
    }
}